// Round 1
// baseline (905.438 us; speedup 1.0000x reference)
//
#include <hip/hip_runtime.h>
#include <stdint.h>

#define BATCH 16
#define NDET 25200
#define NCLS 80
#define PREDC 85
#define KTOP 2048
#define MAXDET 300
#define OUTC 86
#define CONF_THR 0.4f
#define IOU_THR 0.45f
#define MAXWH 4096.0f

// ---- monotone float<->uint mapping (ascending) ----
__device__ __forceinline__ uint32_t mono_f32(float f) {
  uint32_t u = __float_as_uint(f);
  return (u & 0x80000000u) ? ~u : (u | 0x80000000u);
}
__device__ __forceinline__ float unmono_f32(uint32_t m) {
  uint32_t u = (m & 0x80000000u) ? (m & 0x7FFFFFFFu) : ~m;
  return __uint_as_float(u);
}

// K1: per-candidate score/class -> packed sort key.
// key = (~mono(score)) << 32 | (n<<7) | cls   (ascending key == top_k order)
__global__ void k_keys(const float* __restrict__ pred, uint64_t* __restrict__ keys) {
  int idx = blockIdx.x * blockDim.x + threadIdx.x;
  if (idx >= BATCH * NDET) return;
  int n = idx % NDET;
  const float* p = pred + (size_t)idx * PREDC;
  float obj = p[4];
  float best = -1e30f;
  int bc = 0;
  for (int c = 0; c < NCLS; ++c) {
    float s = __fmul_rn(p[5 + c], obj);   // single-rounded, no contraction
    if (s > best) { best = s; bc = c; }   // strict > : first max (argmax semantics)
  }
  bool valid = (obj > CONF_THR) && (best > CONF_THR);
  float score = valid ? best : -1.0f;
  uint64_t key = ((uint64_t)(~mono_f32(score)) << 32) |
                 (uint64_t)(((uint32_t)n << 7) | (uint32_t)bc);
  keys[idx] = key;
}

// K2: per-batch exact 2048-th smallest key via MSB-first radix select.
__global__ void k_select(const uint64_t* __restrict__ keys, uint64_t* __restrict__ kth) {
  __shared__ uint32_t hist[256];
  __shared__ uint64_t prefix_s;
  __shared__ int k_s;
  int b = blockIdx.x;
  const uint64_t* kb = keys + (size_t)b * NDET;
  if (threadIdx.x == 0) { prefix_s = 0; k_s = KTOP; }
  for (int shift = 56; shift >= 0; shift -= 8) {
    __syncthreads();
    for (int i = threadIdx.x; i < 256; i += blockDim.x) hist[i] = 0;
    __syncthreads();
    uint64_t pref = prefix_s;
    for (int n = threadIdx.x; n < NDET; n += blockDim.x) {
      uint64_t key = kb[n];
      if (shift == 56 || (key >> (shift + 8)) == pref)
        atomicAdd(&hist[(uint32_t)((key >> shift) & 255u)], 1u);
    }
    __syncthreads();
    if (threadIdx.x == 0) {
      int k = k_s;
      uint32_t cum = 0;
      int d = 0;
      for (; d < 256; ++d) {
        if (cum + hist[d] >= (uint32_t)k) break;
        cum += hist[d];
      }
      k_s = k - (int)cum;
      prefix_s = (pref << 8) | (uint64_t)d;
    }
  }
  __syncthreads();
  if (threadIdx.x == 0) kth[b] = prefix_s;
}

// K3: compact the exactly-2048 keys <= kth (keys are distinct). Order fixed later.
__global__ void k_collect(const uint64_t* __restrict__ keys, const uint64_t* __restrict__ kth,
                          uint32_t* __restrict__ cnt, uint64_t* __restrict__ topk) {
  int idx = blockIdx.x * blockDim.x + threadIdx.x;
  if (idx >= BATCH * NDET) return;
  int b = idx / NDET;
  uint64_t key = keys[idx];
  if (key <= kth[b]) {
    uint32_t pos = atomicAdd(&cnt[b], 1u);
    if (pos < KTOP) topk[(size_t)b * KTOP + pos] = key;
  }
}

// K4: per-batch bitonic sort (ascending key == descending score), derive arrays.
__global__ void __launch_bounds__(256) k_sort(
    const uint64_t* __restrict__ topk, const float* __restrict__ pred,
    uint32_t* __restrict__ s_n, float* __restrict__ s_score, float* __restrict__ s_clsf,
    float* __restrict__ s_box, float* __restrict__ s_obox, uint32_t* __restrict__ nvalid) {
  __shared__ uint64_t sk[KTOP];
  __shared__ uint32_t nv;
  int b = blockIdx.x, tid = threadIdx.x;
  for (int i = tid; i < KTOP; i += 256) sk[i] = topk[(size_t)b * KTOP + i];
  if (tid == 0) nv = 0;
  for (int kk = 2; kk <= KTOP; kk <<= 1) {
    for (int j = kk >> 1; j > 0; j >>= 1) {
      __syncthreads();
      for (int i = tid; i < KTOP; i += 256) {
        int ixj = i ^ j;
        if (ixj > i) {
          uint64_t a = sk[i], c = sk[ixj];
          bool asc = ((i & kk) == 0);
          if ((a > c) == asc) { sk[i] = c; sk[ixj] = a; }
        }
      }
    }
  }
  __syncthreads();
  for (int r = tid; r < KTOP; r += 256) {
    uint64_t key = sk[r];
    float score = unmono_f32(~(uint32_t)(key >> 32));
    uint32_t low = (uint32_t)key;
    uint32_t n = low >> 7;
    uint32_t cls = low & 127u;
    if (score > 0.0f) atomicAdd(&nv, 1u);
    const float* p = pred + ((size_t)b * NDET + n) * PREDC;
    float x = p[0], y = p[1], w = p[2], h = p[3];
    float hw = __fmul_rn(w, 0.5f), hh = __fmul_rn(h, 0.5f);
    float x1 = __fsub_rn(x, hw), y1 = __fsub_rn(y, hh);
    float x2 = __fadd_rn(x, hw), y2 = __fadd_rn(y, hh);
    float clsf = (float)cls;
    float off = __fmul_rn(clsf, MAXWH);
    size_t o = (size_t)b * KTOP + r;
    s_n[o] = n;
    s_score[o] = score;
    s_clsf[o] = clsf;
    s_box[o * 4 + 0] = x1; s_box[o * 4 + 1] = y1;
    s_box[o * 4 + 2] = x2; s_box[o * 4 + 3] = y2;
    s_obox[o * 4 + 0] = __fadd_rn(x1, off); s_obox[o * 4 + 1] = __fadd_rn(y1, off);
    s_obox[o * 4 + 2] = __fadd_rn(x2, off); s_obox[o * 4 + 3] = __fadd_rn(y2, off);
  }
  __syncthreads();
  if (tid == 0) nvalid[b] = nv;
}

// K5: suppression bitmask. mask[b][i][w] bit t = (j=w*32+t > i) && IoU(off_i,off_j) > 0.45
__global__ void k_mask(const float* __restrict__ s_obox, const uint32_t* __restrict__ nvalid,
                       uint32_t* __restrict__ mask) {
  int gid = blockIdx.x * blockDim.x + threadIdx.x; // BATCH*KTOP*64 threads
  int w = gid & 63;
  int i = (gid >> 6) & (KTOP - 1);
  int b = gid >> 17;
  if (i >= (int)nvalid[b]) return;
  const float* bi = s_obox + ((size_t)b * KTOP + i) * 4;
  float ix1 = bi[0], iy1 = bi[1], ix2 = bi[2], iy2 = bi[3];
  float iarea = __fmul_rn(__fsub_rn(ix2, ix1), __fsub_rn(iy2, iy1));
  uint32_t word = 0;
  int j0 = w * 32;
  for (int t = 0; t < 32; ++t) {
    int j = j0 + t;
    if (j <= i) continue;
    const float* bj = s_obox + ((size_t)b * KTOP + j) * 4;
    float jx1 = bj[0], jy1 = bj[1], jx2 = bj[2], jy2 = bj[3];
    float jarea = __fmul_rn(__fsub_rn(jx2, jx1), __fsub_rn(jy2, jy1));
    float ltx = fmaxf(ix1, jx1), lty = fmaxf(iy1, jy1);
    float rbx = fminf(ix2, jx2), rby = fminf(iy2, jy2);
    float wx = fmaxf(__fsub_rn(rbx, ltx), 0.0f);
    float wy = fmaxf(__fsub_rn(rby, lty), 0.0f);
    float inter = __fmul_rn(wx, wy);
    float denom = __fadd_rn(__fsub_rn(__fadd_rn(iarea, jarea), inter), 1e-7f);
    float iou = __fdiv_rn(inter, denom);
    if (iou > IOU_THR) word |= (1u << t);
  }
  mask[((size_t)b * KTOP + i) * 64 + w] = word;
}

// K6: sequential greedy pass. One wave per batch; lane l owns removed bits [32l,32l+32).
#define NMSD 16
__global__ void k_nms(const uint32_t* __restrict__ mask, const uint32_t* __restrict__ nvalid,
                      uint32_t* __restrict__ supp) {
  int b = blockIdx.x;
  int lane = threadIdx.x; // 64 threads = 1 wave
  int nv = (int)nvalid[b];
  const uint32_t* mb = mask + (size_t)b * KTOP * 64;
  uint32_t removed = 0;
  auto ld = [&](int i) -> uint32_t {
    return (i < nv) ? mb[(size_t)i * 64 + lane] : 0u;
  };
  uint32_t buf[NMSD];
#pragma unroll
  for (int d = 0; d < NMSD; ++d) buf[d] = ld(d);
  for (int base = 0; base < nv; base += NMSD) {
#pragma unroll
    for (int d = 0; d < NMSD; ++d) {
      int i = base + d;
      if (i < nv) {
        uint32_t rw = __shfl(removed, i >> 5);
        if (!((rw >> (i & 31)) & 1u)) removed |= buf[d];
      }
      buf[d] = ld(base + d + NMSD);
    }
  }
  supp[b * 64 + lane] = removed;
}

// K7: compact kept rows to output (out must be pre-zeroed).
__global__ void __launch_bounds__(256) k_out(
    const uint32_t* __restrict__ supp, const uint32_t* __restrict__ nvalid,
    const uint32_t* __restrict__ s_n, const float* __restrict__ s_score,
    const float* __restrict__ s_clsf, const float* __restrict__ s_box,
    const float* __restrict__ logits, float* __restrict__ out) {
  __shared__ uint32_t keepw[64];
  __shared__ uint32_t pfx[64];
  int b = blockIdx.x, tid = threadIdx.x;
  int nv = (int)nvalid[b];
  if (tid < 64) {
    uint32_t sw = supp[b * 64 + tid];
    int lo = tid * 32;
    uint32_t vm;
    if (nv >= lo + 32) vm = 0xFFFFFFFFu;
    else if (nv <= lo) vm = 0u;
    else vm = (1u << (nv - lo)) - 1u;
    keepw[tid] = (~sw) & vm;
  }
  __syncthreads();
  if (tid == 0) {
    uint32_t c = 0;
    for (int w = 0; w < 64; ++w) { pfx[w] = c; c += __popc(keepw[w]); }
  }
  __syncthreads();
  for (int r = tid; r < KTOP; r += 256) {
    int w = r >> 5, t = r & 31;
    uint32_t kw = keepw[w];
    if (!((kw >> t) & 1u)) continue;
    uint32_t rank = pfx[w] + (uint32_t)__popc(kw & ((1u << t) - 1u));
    if (rank >= MAXDET) continue;
    size_t o = (size_t)b * KTOP + r;
    float* orow = out + ((size_t)b * MAXDET + rank) * OUTC;
    orow[0] = s_box[o * 4 + 0];
    orow[1] = s_box[o * 4 + 1];
    orow[2] = s_box[o * 4 + 2];
    orow[3] = s_box[o * 4 + 3];
    orow[4] = s_score[o];
    orow[5] = s_clsf[o];
    const float* lrow = logits + ((size_t)b * NDET + s_n[o]) * NCLS;
    for (int c2 = 0; c2 < NCLS; ++c2) orow[6 + c2] = lrow[c2];
  }
}

extern "C" void kernel_launch(void* const* d_in, const int* in_sizes, int n_in,
                              void* d_out, int out_size, void* d_ws, size_t ws_size,
                              hipStream_t stream) {
  const float* pred = (const float*)d_in[0];
  const float* logits = (const float*)d_in[1];
  float* out = (float*)d_out;

  char* ws = (char*)d_ws;
  size_t off = 0;
  auto alloc = [&](size_t bytes) -> void* {
    void* p = ws + off;
    off += (bytes + 255) & ~(size_t)255;
    return p;
  };
  uint64_t* keys  = (uint64_t*)alloc((size_t)BATCH * NDET * 8);
  uint64_t* kth   = (uint64_t*)alloc((size_t)BATCH * 8);
  uint64_t* topk  = (uint64_t*)alloc((size_t)BATCH * KTOP * 8);
  uint32_t* cnt   = (uint32_t*)alloc((size_t)BATCH * 4);
  uint32_t* s_n   = (uint32_t*)alloc((size_t)BATCH * KTOP * 4);
  float*    s_sc  = (float*)alloc((size_t)BATCH * KTOP * 4);
  float*    s_cl  = (float*)alloc((size_t)BATCH * KTOP * 4);
  float*    s_box = (float*)alloc((size_t)BATCH * KTOP * 16);
  float*    s_ob  = (float*)alloc((size_t)BATCH * KTOP * 16);
  uint32_t* nval  = (uint32_t*)alloc((size_t)BATCH * 4);
  uint32_t* mask  = (uint32_t*)alloc((size_t)BATCH * KTOP * 64 * 4);
  uint32_t* suppw = (uint32_t*)alloc((size_t)BATCH * 64 * 4);
  (void)ws_size; (void)in_sizes; (void)n_in;

  hipMemsetAsync(d_out, 0, (size_t)out_size * sizeof(float), stream);
  hipMemsetAsync(cnt, 0, (size_t)BATCH * 4, stream);

  int total = BATCH * NDET;
  k_keys<<<(total + 255) / 256, 256, 0, stream>>>(pred, keys);
  k_select<<<BATCH, 256, 0, stream>>>(keys, kth);
  k_collect<<<(total + 255) / 256, 256, 0, stream>>>(keys, kth, cnt, topk);
  k_sort<<<BATCH, 256, 0, stream>>>(topk, pred, s_n, s_sc, s_cl, s_box, s_ob, nval);
  k_mask<<<(BATCH * KTOP * 64) / 256, 256, 0, stream>>>(s_ob, nval, mask);
  k_nms<<<BATCH, 64, 0, stream>>>(mask, nval, suppw);
  k_out<<<BATCH, 256, 0, stream>>>(suppw, nval, s_n, s_sc, s_cl, s_box, logits, out);
}

// Round 2
// 404.443 us; speedup vs baseline: 2.2387x; 2.2387x over previous
//
#include <hip/hip_runtime.h>
#include <stdint.h>

#define BATCH 16
#define NDET 25200
#define NCLS 80
#define PREDC 85
#define KTOP 2048
#define MAXDET 300
#define OUTC 86
#define CONF_THR 0.4f
#define IOU_THR 0.45f
#define MAXWH 4096.0f

// ---- monotone float<->uint mapping (ascending) ----
__device__ __forceinline__ uint32_t mono_f32(float f) {
  uint32_t u = __float_as_uint(f);
  return (u & 0x80000000u) ? ~u : (u | 0x80000000u);
}
__device__ __forceinline__ float unmono_f32(uint32_t m) {
  uint32_t u = (m & 0x80000000u) ? (m & 0x7FFFFFFFu) : ~m;
  return __uint_as_float(u);
}

// K1: per-candidate score/class -> packed sort key.
// key = (~mono(score)) << 32 | (n<<7) | cls   (ascending key == top_k order)
__global__ void k_keys(const float* __restrict__ pred, uint64_t* __restrict__ keys) {
  int idx = blockIdx.x * blockDim.x + threadIdx.x;
  if (idx >= BATCH * NDET) return;
  int n = idx % NDET;
  const float* p = pred + (size_t)idx * PREDC;
  float obj = p[4];
  float best = -1e30f;
  int bc = 0;
  for (int c = 0; c < NCLS; ++c) {
    float s = __fmul_rn(p[5 + c], obj);   // single-rounded, no contraction
    if (s > best) { best = s; bc = c; }   // strict > : first max (argmax semantics)
  }
  bool valid = (obj > CONF_THR) && (best > CONF_THR);
  float score = valid ? best : -1.0f;
  uint64_t key = ((uint64_t)(~mono_f32(score)) << 32) |
                 (uint64_t)(((uint32_t)n << 7) | (uint32_t)bc);
  keys[idx] = key;
}

// K2 (fused select+collect+sort+derive), one 1024-thread block per batch.
// - MSB-first radix select finds exact 2048th-smallest key (keys distinct).
// - Wave-aggregated collection into LDS (no global atomics).
// - Bitonic sort 2048 keys in LDS (ascending key == lax.top_k order).
// - Derive box / offset-box / score / cls / n arrays.
__global__ void __launch_bounds__(1024) k_sel(
    const uint64_t* __restrict__ keys, const float* __restrict__ pred,
    uint32_t* __restrict__ s_n, float* __restrict__ s_score, float* __restrict__ s_clsf,
    float* __restrict__ s_box, float* __restrict__ s_obox, uint32_t* __restrict__ nvalid) {
  __shared__ uint64_t sk[KTOP];
  __shared__ uint32_t hist[256];
  __shared__ uint64_t prefix_s;
  __shared__ uint32_t k_s;
  __shared__ uint32_t ncol;
  __shared__ uint32_t nv;
  int b = blockIdx.x, tid = threadIdx.x;
  int lane = tid & 63;
  const uint64_t* kb = keys + (size_t)b * NDET;
  if (tid == 0) { prefix_s = 0; k_s = KTOP; ncol = 0; nv = 0; }

  // --- radix select, 8 passes of 8 bits (MSB first) ---
  for (int shift = 56; shift >= 0; shift -= 8) {
    __syncthreads();
    if (tid < 256) hist[tid] = 0;
    __syncthreads();
    uint64_t pref = prefix_s;
    for (int n = tid; n < NDET; n += 1024) {
      uint64_t key = kb[n];
      if (shift == 56 || (key >> (shift + 8)) == pref)
        atomicAdd(&hist[(uint32_t)((key >> shift) & 255u)], 1u);
    }
    __syncthreads();
    if (tid == 0) {
      uint32_t k = k_s, cum = 0;
      int d = 0;
      for (; d < 256; ++d) {
        if (cum + hist[d] >= k) break;
        cum += hist[d];
      }
      k_s = k - cum;
      prefix_s = (pref << 8) | (uint64_t)d;
    }
  }
  __syncthreads();
  uint64_t kth = prefix_s;

  // --- collect: exactly KTOP keys <= kth; wave-aggregated LDS append ---
  for (int n = tid; n < NDET; n += 1024) {
    uint64_t key = kb[n];
    bool p = (key <= kth);
    uint64_t ball = __ballot(p);
    uint32_t base = 0;
    if (lane == 0) base = atomicAdd(&ncol, (uint32_t)__popcll(ball));
    base = __shfl(base, 0);
    if (p) {
      uint32_t pos = base + (uint32_t)__popcll(ball & ((1ull << lane) - 1ull));
      if (pos < KTOP) sk[pos] = key;
    }
  }

  // --- bitonic sort ascending ---
  for (int kk = 2; kk <= KTOP; kk <<= 1) {
    for (int j = kk >> 1; j > 0; j >>= 1) {
      __syncthreads();
      for (int i = tid; i < KTOP; i += 1024) {
        int ixj = i ^ j;
        if (ixj > i) {
          uint64_t a = sk[i], c = sk[ixj];
          bool asc = ((i & kk) == 0);
          if ((a > c) == asc) { sk[i] = c; sk[ixj] = a; }
        }
      }
    }
  }
  __syncthreads();

  // --- derive arrays ---
  for (int r = tid; r < KTOP; r += 1024) {
    uint64_t key = sk[r];
    float score = unmono_f32(~(uint32_t)(key >> 32));
    uint32_t low = (uint32_t)key;
    uint32_t n = low >> 7;
    uint32_t cls = low & 127u;
    uint64_t vball = __ballot(score > 0.0f);
    if (lane == 0) atomicAdd(&nv, (uint32_t)__popcll(vball));
    const float* p = pred + ((size_t)b * NDET + n) * PREDC;
    float x = p[0], y = p[1], w = p[2], h = p[3];
    float hw = __fmul_rn(w, 0.5f), hh = __fmul_rn(h, 0.5f);
    float x1 = __fsub_rn(x, hw), y1 = __fsub_rn(y, hh);
    float x2 = __fadd_rn(x, hw), y2 = __fadd_rn(y, hh);
    float clsf = (float)cls;
    float off = __fmul_rn(clsf, MAXWH);
    size_t o = (size_t)b * KTOP + r;
    s_n[o] = n;
    s_score[o] = score;
    s_clsf[o] = clsf;
    s_box[o * 4 + 0] = x1; s_box[o * 4 + 1] = y1;
    s_box[o * 4 + 2] = x2; s_box[o * 4 + 3] = y2;
    s_obox[o * 4 + 0] = __fadd_rn(x1, off); s_obox[o * 4 + 1] = __fadd_rn(y1, off);
    s_obox[o * 4 + 2] = __fadd_rn(x2, off); s_obox[o * 4 + 3] = __fadd_rn(y2, off);
  }
  __syncthreads();
  if (tid == 0) nvalid[b] = nv;
}

// K5: suppression bitmask. mask[b][i][w] bit t = (j=w*32+t > i) && IoU(off_i,off_j) > 0.45
__global__ void k_mask(const float* __restrict__ s_obox, const uint32_t* __restrict__ nvalid,
                       uint32_t* __restrict__ mask) {
  int gid = blockIdx.x * blockDim.x + threadIdx.x; // BATCH*KTOP*64 threads
  int w = gid & 63;
  int i = (gid >> 6) & (KTOP - 1);
  int b = gid >> 17;
  if (i >= (int)nvalid[b]) return;
  const float* bi = s_obox + ((size_t)b * KTOP + i) * 4;
  float ix1 = bi[0], iy1 = bi[1], ix2 = bi[2], iy2 = bi[3];
  float iarea = __fmul_rn(__fsub_rn(ix2, ix1), __fsub_rn(iy2, iy1));
  uint32_t word = 0;
  int j0 = w * 32;
  for (int t = 0; t < 32; ++t) {
    int j = j0 + t;
    if (j <= i) continue;
    const float* bj = s_obox + ((size_t)b * KTOP + j) * 4;
    float jx1 = bj[0], jy1 = bj[1], jx2 = bj[2], jy2 = bj[3];
    float jarea = __fmul_rn(__fsub_rn(jx2, jx1), __fsub_rn(jy2, jy1));
    float ltx = fmaxf(ix1, jx1), lty = fmaxf(iy1, jy1);
    float rbx = fminf(ix2, jx2), rby = fminf(iy2, jy2);
    float wx = fmaxf(__fsub_rn(rbx, ltx), 0.0f);
    float wy = fmaxf(__fsub_rn(rby, lty), 0.0f);
    float inter = __fmul_rn(wx, wy);
    float denom = __fadd_rn(__fsub_rn(__fadd_rn(iarea, jarea), inter), 1e-7f);
    float iou = __fdiv_rn(inter, denom);
    if (iou > IOU_THR) word |= (1u << t);
  }
  mask[((size_t)b * KTOP + i) * 64 + w] = word;
}

// K6: sequential greedy pass. One wave per batch; lane l owns removed bits [32l,32l+32).
#define NMSD 16
__global__ void k_nms(const uint32_t* __restrict__ mask, const uint32_t* __restrict__ nvalid,
                      uint32_t* __restrict__ supp) {
  int b = blockIdx.x;
  int lane = threadIdx.x; // 64 threads = 1 wave
  int nv = (int)nvalid[b];
  const uint32_t* mb = mask + (size_t)b * KTOP * 64;
  uint32_t removed = 0;
  auto ld = [&](int i) -> uint32_t {
    return (i < nv) ? mb[(size_t)i * 64 + lane] : 0u;
  };
  uint32_t buf[NMSD];
#pragma unroll
  for (int d = 0; d < NMSD; ++d) buf[d] = ld(d);
  for (int base = 0; base < nv; base += NMSD) {
#pragma unroll
    for (int d = 0; d < NMSD; ++d) {
      int i = base + d;
      if (i < nv) {
        uint32_t rw = __shfl(removed, i >> 5);
        if (!((rw >> (i & 31)) & 1u)) removed |= buf[d];
      }
      buf[d] = ld(base + d + NMSD);
    }
  }
  supp[b * 64 + lane] = removed;
}

// K7: compact kept rows to output (out must be pre-zeroed).
__global__ void __launch_bounds__(256) k_out(
    const uint32_t* __restrict__ supp, const uint32_t* __restrict__ nvalid,
    const uint32_t* __restrict__ s_n, const float* __restrict__ s_score,
    const float* __restrict__ s_clsf, const float* __restrict__ s_box,
    const float* __restrict__ logits, float* __restrict__ out) {
  __shared__ uint32_t keepw[64];
  __shared__ uint32_t pfx[64];
  int b = blockIdx.x, tid = threadIdx.x;
  int nv = (int)nvalid[b];
  if (tid < 64) {
    uint32_t sw = supp[b * 64 + tid];
    int lo = tid * 32;
    uint32_t vm;
    if (nv >= lo + 32) vm = 0xFFFFFFFFu;
    else if (nv <= lo) vm = 0u;
    else vm = (1u << (nv - lo)) - 1u;
    keepw[tid] = (~sw) & vm;
  }
  __syncthreads();
  if (tid == 0) {
    uint32_t c = 0;
    for (int w = 0; w < 64; ++w) { pfx[w] = c; c += __popc(keepw[w]); }
  }
  __syncthreads();
  for (int r = tid; r < KTOP; r += 256) {
    int w = r >> 5, t = r & 31;
    uint32_t kw = keepw[w];
    if (!((kw >> t) & 1u)) continue;
    uint32_t rank = pfx[w] + (uint32_t)__popc(kw & ((1u << t) - 1u));
    if (rank >= MAXDET) continue;
    size_t o = (size_t)b * KTOP + r;
    float* orow = out + ((size_t)b * MAXDET + rank) * OUTC;
    orow[0] = s_box[o * 4 + 0];
    orow[1] = s_box[o * 4 + 1];
    orow[2] = s_box[o * 4 + 2];
    orow[3] = s_box[o * 4 + 3];
    orow[4] = s_score[o];
    orow[5] = s_clsf[o];
    const float* lrow = logits + ((size_t)b * NDET + s_n[o]) * NCLS;
    for (int c2 = 0; c2 < NCLS; ++c2) orow[6 + c2] = lrow[c2];
  }
}

extern "C" void kernel_launch(void* const* d_in, const int* in_sizes, int n_in,
                              void* d_out, int out_size, void* d_ws, size_t ws_size,
                              hipStream_t stream) {
  const float* pred = (const float*)d_in[0];
  const float* logits = (const float*)d_in[1];
  float* out = (float*)d_out;

  char* ws = (char*)d_ws;
  size_t off = 0;
  auto alloc = [&](size_t bytes) -> void* {
    void* p = ws + off;
    off += (bytes + 255) & ~(size_t)255;
    return p;
  };
  uint64_t* keys  = (uint64_t*)alloc((size_t)BATCH * NDET * 8);
  uint32_t* s_n   = (uint32_t*)alloc((size_t)BATCH * KTOP * 4);
  float*    s_sc  = (float*)alloc((size_t)BATCH * KTOP * 4);
  float*    s_cl  = (float*)alloc((size_t)BATCH * KTOP * 4);
  float*    s_box = (float*)alloc((size_t)BATCH * KTOP * 16);
  float*    s_ob  = (float*)alloc((size_t)BATCH * KTOP * 16);
  uint32_t* nval  = (uint32_t*)alloc((size_t)BATCH * 4);
  uint32_t* mask  = (uint32_t*)alloc((size_t)BATCH * KTOP * 64 * 4);
  uint32_t* suppw = (uint32_t*)alloc((size_t)BATCH * 64 * 4);
  (void)ws_size; (void)in_sizes; (void)n_in;

  hipMemsetAsync(d_out, 0, (size_t)out_size * sizeof(float), stream);

  int total = BATCH * NDET;
  k_keys<<<(total + 255) / 256, 256, 0, stream>>>(pred, keys);
  k_sel<<<BATCH, 1024, 0, stream>>>(keys, pred, s_n, s_sc, s_cl, s_box, s_ob, nval);
  k_mask<<<(BATCH * KTOP * 64) / 256, 256, 0, stream>>>(s_ob, nval, mask);
  k_nms<<<BATCH, 64, 0, stream>>>(mask, nval, suppw);
  k_out<<<BATCH, 256, 0, stream>>>(suppw, nval, s_n, s_sc, s_cl, s_box, logits, out);
}

// Round 3
// 379.940 us; speedup vs baseline: 2.3831x; 1.0645x over previous
//
#include <hip/hip_runtime.h>
#include <stdint.h>

#define BATCH 16
#define NDET 25200
#define NCLS 80
#define PREDC 85
#define KTOP 2048
#define MAXDET 300
#define OUTC 86
#define CONF_THR 0.4f
#define IOU_THR 0.45f
#define MAXWH 4096.0f

// ---- monotone float<->uint mapping (ascending) ----
__device__ __forceinline__ uint32_t mono_f32(float f) {
  uint32_t u = __float_as_uint(f);
  return (u & 0x80000000u) ? ~u : (u | 0x80000000u);
}
__device__ __forceinline__ float unmono_f32(uint32_t m) {
  uint32_t u = (m & 0x80000000u) ? (m & 0x7FFFFFFFu) : ~m;
  return __uint_as_float(u);
}

// K1: per-candidate score/class -> packed sort key.
// key = (~mono(score)) << 32 | (n<<7) | cls   (ascending key == top_k order)
__global__ void k_keys(const float* __restrict__ pred, uint64_t* __restrict__ keys) {
  int idx = blockIdx.x * blockDim.x + threadIdx.x;
  if (idx >= BATCH * NDET) return;
  int n = idx % NDET;
  const float* p = pred + (size_t)idx * PREDC;
  float obj = p[4];
  float best = -1e30f;
  int bc = 0;
  for (int c = 0; c < NCLS; ++c) {
    float s = __fmul_rn(p[5 + c], obj);   // single-rounded, no contraction
    if (s > best) { best = s; bc = c; }   // strict > : first max (argmax semantics)
  }
  bool valid = (obj > CONF_THR) && (best > CONF_THR);
  float score = valid ? best : -1.0f;
  uint64_t key = ((uint64_t)(~mono_f32(score)) << 32) |
                 (uint64_t)(((uint32_t)n << 7) | (uint32_t)bc);
  keys[idx] = key;
}

// K2 (fused select+collect+sort+derive), one 1024-thread block per batch.
__global__ void __launch_bounds__(1024) k_sel(
    const uint64_t* __restrict__ keys, const float* __restrict__ pred,
    uint32_t* __restrict__ s_n, float* __restrict__ s_score, float* __restrict__ s_clsf,
    float* __restrict__ s_box, float* __restrict__ s_obox, uint32_t* __restrict__ nvalid) {
  __shared__ uint64_t sk[KTOP];
  __shared__ uint32_t hist[256];
  __shared__ uint64_t prefix_s;
  __shared__ uint32_t k_s;
  __shared__ uint32_t ncol;
  __shared__ uint32_t nv;
  int b = blockIdx.x, tid = threadIdx.x;
  int lane = tid & 63;
  const uint64_t* kb = keys + (size_t)b * NDET;
  if (tid == 0) { prefix_s = 0; k_s = KTOP; ncol = 0; nv = 0; }

  // --- radix select, 8 passes of 8 bits (MSB first) ---
  for (int shift = 56; shift >= 0; shift -= 8) {
    __syncthreads();
    if (tid < 256) hist[tid] = 0;
    __syncthreads();
    uint64_t pref = prefix_s;
    for (int n = tid; n < NDET; n += 1024) {
      uint64_t key = kb[n];
      if (shift == 56 || (key >> (shift + 8)) == pref)
        atomicAdd(&hist[(uint32_t)((key >> shift) & 255u)], 1u);
    }
    __syncthreads();
    if (tid == 0) {
      uint32_t k = k_s, cum = 0;
      int d = 0;
      for (; d < 256; ++d) {
        if (cum + hist[d] >= k) break;
        cum += hist[d];
      }
      k_s = k - cum;
      prefix_s = (pref << 8) | (uint64_t)d;
    }
  }
  __syncthreads();
  uint64_t kth = prefix_s;

  // --- collect: exactly KTOP keys <= kth; wave-aggregated LDS append ---
  for (int n = tid; n < NDET; n += 1024) {
    uint64_t key = kb[n];
    bool p = (key <= kth);
    uint64_t ball = __ballot(p);
    uint32_t base = 0;
    if (lane == 0) base = atomicAdd(&ncol, (uint32_t)__popcll(ball));
    base = __shfl(base, 0);
    if (p) {
      uint32_t pos = base + (uint32_t)__popcll(ball & ((1ull << lane) - 1ull));
      if (pos < KTOP) sk[pos] = key;
    }
  }

  // --- bitonic sort ascending ---
  for (int kk = 2; kk <= KTOP; kk <<= 1) {
    for (int j = kk >> 1; j > 0; j >>= 1) {
      __syncthreads();
      for (int i = tid; i < KTOP; i += 1024) {
        int ixj = i ^ j;
        if (ixj > i) {
          uint64_t a = sk[i], c = sk[ixj];
          bool asc = ((i & kk) == 0);
          if ((a > c) == asc) { sk[i] = c; sk[ixj] = a; }
        }
      }
    }
  }
  __syncthreads();

  // --- derive arrays ---
  for (int r = tid; r < KTOP; r += 1024) {
    uint64_t key = sk[r];
    float score = unmono_f32(~(uint32_t)(key >> 32));
    uint32_t low = (uint32_t)key;
    uint32_t n = low >> 7;
    uint32_t cls = low & 127u;
    uint64_t vball = __ballot(score > 0.0f);
    if (lane == 0) atomicAdd(&nv, (uint32_t)__popcll(vball));
    const float* p = pred + ((size_t)b * NDET + n) * PREDC;
    float x = p[0], y = p[1], w = p[2], h = p[3];
    float hw = __fmul_rn(w, 0.5f), hh = __fmul_rn(h, 0.5f);
    float x1 = __fsub_rn(x, hw), y1 = __fsub_rn(y, hh);
    float x2 = __fadd_rn(x, hw), y2 = __fadd_rn(y, hh);
    float clsf = (float)cls;
    float off = __fmul_rn(clsf, MAXWH);
    size_t o = (size_t)b * KTOP + r;
    s_n[o] = n;
    s_score[o] = score;
    s_clsf[o] = clsf;
    s_box[o * 4 + 0] = x1; s_box[o * 4 + 1] = y1;
    s_box[o * 4 + 2] = x2; s_box[o * 4 + 3] = y2;
    s_obox[o * 4 + 0] = __fadd_rn(x1, off); s_obox[o * 4 + 1] = __fadd_rn(y1, off);
    s_obox[o * 4 + 2] = __fadd_rn(x2, off); s_obox[o * 4 + 3] = __fadd_rn(y2, off);
  }
  __syncthreads();
  if (tid == 0) nvalid[b] = nv;
}

// K5: suppression bitmask. mask[b][i][w] bit t = (j=w*32+t > i) && IoU(off_i,off_j) > 0.45
__global__ void k_mask(const float* __restrict__ s_obox, const uint32_t* __restrict__ nvalid,
                       uint32_t* __restrict__ mask) {
  int gid = blockIdx.x * blockDim.x + threadIdx.x; // BATCH*KTOP*64 threads
  int w = gid & 63;
  int i = (gid >> 6) & (KTOP - 1);
  int b = gid >> 17;
  if (i >= (int)nvalid[b]) return;
  const float* bi = s_obox + ((size_t)b * KTOP + i) * 4;
  float ix1 = bi[0], iy1 = bi[1], ix2 = bi[2], iy2 = bi[3];
  float iarea = __fmul_rn(__fsub_rn(ix2, ix1), __fsub_rn(iy2, iy1));
  uint32_t word = 0;
  int j0 = w * 32;
  for (int t = 0; t < 32; ++t) {
    int j = j0 + t;
    if (j <= i) continue;
    const float* bj = s_obox + ((size_t)b * KTOP + j) * 4;
    float jx1 = bj[0], jy1 = bj[1], jx2 = bj[2], jy2 = bj[3];
    float jarea = __fmul_rn(__fsub_rn(jx2, jx1), __fsub_rn(jy2, jy1));
    float ltx = fmaxf(ix1, jx1), lty = fmaxf(iy1, jy1);
    float rbx = fminf(ix2, jx2), rby = fminf(iy2, jy2);
    float wx = fmaxf(__fsub_rn(rbx, ltx), 0.0f);
    float wy = fmaxf(__fsub_rn(rby, lty), 0.0f);
    float inter = __fmul_rn(wx, wy);
    float denom = __fadd_rn(__fsub_rn(__fadd_rn(iarea, jarea), inter), 1e-7f);
    float iou = __fdiv_rn(inter, denom);
    if (iou > IOU_THR) word |= (1u << t);
  }
  mask[((size_t)b * KTOP + i) * 64 + w] = word;
}

// K6: sequential greedy pass, one wave per batch; lane l owns removed word l.
// Group-of-32 structure keeps the cross-lane shfl OFF the serial chain:
// curw (word g, replicated in all lanes) is updated with shfl(buf[d], g),
// which depends only on prefetched data. Critical path = 4 VALU ops/iter.
__global__ void k_nms(const uint32_t* __restrict__ mask, const uint32_t* __restrict__ nvalid,
                      uint32_t* __restrict__ supp) {
  int b = blockIdx.x;
  int lane = threadIdx.x; // 64 threads = 1 wave
  int nv = (int)nvalid[b];
  const uint32_t* mb = mask + (size_t)b * KTOP * 64;
  uint32_t removed = 0;
  uint32_t bufA[32], bufB[32];
#pragma unroll
  for (int d = 0; d < 32; ++d)
    bufA[d] = (d < nv) ? mb[(size_t)d * 64 + lane] : 0u;
  int ngrp = (nv + 31) >> 5;
  for (int g = 0; g < ngrp; ++g) {
    int nbase = (g + 1) * 32;
#pragma unroll
    for (int d = 0; d < 32; ++d) {
      int i = nbase + d;
      bufB[d] = (i < nv) ? mb[(size_t)i * 64 + lane] : 0u;
    }
    uint32_t curw = __shfl(removed, g);
    int base = g * 32;
#pragma unroll
    for (int d = 0; d < 32; ++d) {
      uint32_t bsh = __shfl(bufA[d], g);          // off critical path
      bool alive = ((base + d) < nv) && !((curw >> d) & 1u);
      curw |= alive ? bsh : 0u;                    // serial chain (VALU only)
      removed |= alive ? bufA[d] : 0u;             // per-lane, off-path
    }
#pragma unroll
    for (int d = 0; d < 32; ++d) bufA[d] = bufB[d];
  }
  supp[b * 64 + lane] = removed;
}

// K7: compact kept rows to output (out must be pre-zeroed).
__global__ void __launch_bounds__(256) k_out(
    const uint32_t* __restrict__ supp, const uint32_t* __restrict__ nvalid,
    const uint32_t* __restrict__ s_n, const float* __restrict__ s_score,
    const float* __restrict__ s_clsf, const float* __restrict__ s_box,
    const float* __restrict__ logits, float* __restrict__ out) {
  __shared__ uint32_t keepw[64];
  __shared__ uint32_t pfx[64];
  int b = blockIdx.x, tid = threadIdx.x;
  int nv = (int)nvalid[b];
  if (tid < 64) {
    uint32_t sw = supp[b * 64 + tid];
    int lo = tid * 32;
    uint32_t vm;
    if (nv >= lo + 32) vm = 0xFFFFFFFFu;
    else if (nv <= lo) vm = 0u;
    else vm = (1u << (nv - lo)) - 1u;
    keepw[tid] = (~sw) & vm;
  }
  __syncthreads();
  if (tid == 0) {
    uint32_t c = 0;
    for (int w = 0; w < 64; ++w) { pfx[w] = c; c += __popc(keepw[w]); }
  }
  __syncthreads();
  for (int r = tid; r < KTOP; r += 256) {
    int w = r >> 5, t = r & 31;
    uint32_t kw = keepw[w];
    if (!((kw >> t) & 1u)) continue;
    uint32_t rank = pfx[w] + (uint32_t)__popc(kw & ((1u << t) - 1u));
    if (rank >= MAXDET) continue;
    size_t o = (size_t)b * KTOP + r;
    float* orow = out + ((size_t)b * MAXDET + rank) * OUTC;
    orow[0] = s_box[o * 4 + 0];
    orow[1] = s_box[o * 4 + 1];
    orow[2] = s_box[o * 4 + 2];
    orow[3] = s_box[o * 4 + 3];
    orow[4] = s_score[o];
    orow[5] = s_clsf[o];
    const float* lrow = logits + ((size_t)b * NDET + s_n[o]) * NCLS;
    for (int c2 = 0; c2 < NCLS; ++c2) orow[6 + c2] = lrow[c2];
  }
}

extern "C" void kernel_launch(void* const* d_in, const int* in_sizes, int n_in,
                              void* d_out, int out_size, void* d_ws, size_t ws_size,
                              hipStream_t stream) {
  const float* pred = (const float*)d_in[0];
  const float* logits = (const float*)d_in[1];
  float* out = (float*)d_out;

  char* ws = (char*)d_ws;
  size_t off = 0;
  auto alloc = [&](size_t bytes) -> void* {
    void* p = ws + off;
    off += (bytes + 255) & ~(size_t)255;
    return p;
  };
  uint64_t* keys  = (uint64_t*)alloc((size_t)BATCH * NDET * 8);
  uint32_t* s_n   = (uint32_t*)alloc((size_t)BATCH * KTOP * 4);
  float*    s_sc  = (float*)alloc((size_t)BATCH * KTOP * 4);
  float*    s_cl  = (float*)alloc((size_t)BATCH * KTOP * 4);
  float*    s_box = (float*)alloc((size_t)BATCH * KTOP * 16);
  float*    s_ob  = (float*)alloc((size_t)BATCH * KTOP * 16);
  uint32_t* nval  = (uint32_t*)alloc((size_t)BATCH * 4);
  uint32_t* mask  = (uint32_t*)alloc((size_t)BATCH * KTOP * 64 * 4);
  uint32_t* suppw = (uint32_t*)alloc((size_t)BATCH * 64 * 4);
  (void)ws_size; (void)in_sizes; (void)n_in;

  hipMemsetAsync(d_out, 0, (size_t)out_size * sizeof(float), stream);

  int total = BATCH * NDET;
  k_keys<<<(total + 255) / 256, 256, 0, stream>>>(pred, keys);
  k_sel<<<BATCH, 1024, 0, stream>>>(keys, pred, s_n, s_sc, s_cl, s_box, s_ob, nval);
  k_mask<<<(BATCH * KTOP * 64) / 256, 256, 0, stream>>>(s_ob, nval, mask);
  k_nms<<<BATCH, 64, 0, stream>>>(mask, nval, suppw);
  k_out<<<BATCH, 256, 0, stream>>>(suppw, nval, s_n, s_sc, s_cl, s_box, logits, out);
}

// Round 4
// 371.969 us; speedup vs baseline: 2.4342x; 1.0214x over previous
//
#include <hip/hip_runtime.h>
#include <stdint.h>

#define BATCH 16
#define NDET 25200
#define NCLS 80
#define PREDC 85
#define KTOP 2048
#define MAXDET 300
#define OUTC 86
#define CONF_THR 0.4f
#define IOU_THR 0.45f
#define MAXWH 4096.0f

#define REP32(F) F(0)F(1)F(2)F(3)F(4)F(5)F(6)F(7)F(8)F(9)F(10)F(11)F(12)F(13)F(14)F(15)F(16)F(17)F(18)F(19)F(20)F(21)F(22)F(23)F(24)F(25)F(26)F(27)F(28)F(29)F(30)F(31)

// ---- monotone float<->uint mapping (ascending) ----
__device__ __forceinline__ uint32_t mono_f32(float f) {
  uint32_t u = __float_as_uint(f);
  return (u & 0x80000000u) ? ~u : (u | 0x80000000u);
}
__device__ __forceinline__ float unmono_f32(uint32_t m) {
  uint32_t u = (m & 0x80000000u) ? (m & 0x7FFFFFFFu) : ~m;
  return __uint_as_float(u);
}

// K1: per-candidate score/class -> packed sort key.
// key = (~mono(score)) << 32 | (n<<7) | cls   (ascending key == top_k order)
// Early-out: obj <= CONF_THR rows are invalid regardless of classes; their key
// is (score=-1, cls=0). cls never affects ordering among equal scores (n is
// unique and occupies higher bits) and invalid rows are never emitted.
__global__ void k_keys(const float* __restrict__ pred, uint64_t* __restrict__ keys) {
  int idx = blockIdx.x * blockDim.x + threadIdx.x;
  if (idx >= BATCH * NDET) return;
  int n = idx % NDET;
  const float* p = pred + (size_t)idx * PREDC;
  float obj = p[4];
  float score = -1.0f;
  uint32_t cls = 0;
  if (obj > CONF_THR) {
    float best = -1e30f;
    int bc = 0;
    for (int c = 0; c < NCLS; ++c) {
      float s = __fmul_rn(p[5 + c], obj);   // single-rounded, no contraction
      if (s > best) { best = s; bc = c; }   // strict > : first max (argmax)
    }
    if (best > CONF_THR) { score = best; cls = (uint32_t)bc; }
  }
  uint64_t key = ((uint64_t)(~mono_f32(score)) << 32) |
                 (uint64_t)(((uint32_t)n << 7) | cls);
  keys[idx] = key;
}

// K2 (fused select+collect+sort+derive), one 1024-thread block per batch.
__global__ void __launch_bounds__(1024) k_sel(
    const uint64_t* __restrict__ keys, const float* __restrict__ pred,
    uint32_t* __restrict__ s_n, float* __restrict__ s_score, float* __restrict__ s_clsf,
    float* __restrict__ s_box, float* __restrict__ s_obox, uint32_t* __restrict__ nvalid) {
  __shared__ uint64_t sk[KTOP];
  __shared__ uint32_t hist[256];
  __shared__ uint64_t prefix_s;
  __shared__ uint32_t k_s;
  __shared__ uint32_t ncol;
  __shared__ uint32_t nv;
  int b = blockIdx.x, tid = threadIdx.x;
  int lane = tid & 63;
  const uint64_t* kb = keys + (size_t)b * NDET;
  if (tid == 0) { prefix_s = 0; k_s = KTOP; ncol = 0; nv = 0; }

  // --- radix select, 8 passes of 8 bits (MSB first) ---
  for (int shift = 56; shift >= 0; shift -= 8) {
    __syncthreads();
    if (tid < 256) hist[tid] = 0;
    __syncthreads();
    uint64_t pref = prefix_s;
    for (int n = tid; n < NDET; n += 1024) {
      uint64_t key = kb[n];
      if (shift == 56 || (key >> (shift + 8)) == pref)
        atomicAdd(&hist[(uint32_t)((key >> shift) & 255u)], 1u);
    }
    __syncthreads();
    if (tid == 0) {
      uint32_t k = k_s, cum = 0;
      int d = 0;
      for (; d < 256; ++d) {
        if (cum + hist[d] >= k) break;
        cum += hist[d];
      }
      k_s = k - cum;
      prefix_s = (pref << 8) | (uint64_t)d;
    }
  }
  __syncthreads();
  uint64_t kth = prefix_s;

  // --- collect: exactly KTOP keys <= kth; wave-aggregated LDS append ---
  for (int n = tid; n < NDET; n += 1024) {
    uint64_t key = kb[n];
    bool p = (key <= kth);
    uint64_t ball = __ballot(p);
    uint32_t base = 0;
    if (lane == 0) base = atomicAdd(&ncol, (uint32_t)__popcll(ball));
    base = __shfl(base, 0);
    if (p) {
      uint32_t pos = base + (uint32_t)__popcll(ball & ((1ull << lane) - 1ull));
      if (pos < KTOP) sk[pos] = key;
    }
  }

  // --- bitonic sort ascending ---
  for (int kk = 2; kk <= KTOP; kk <<= 1) {
    for (int j = kk >> 1; j > 0; j >>= 1) {
      __syncthreads();
      for (int i = tid; i < KTOP; i += 1024) {
        int ixj = i ^ j;
        if (ixj > i) {
          uint64_t a = sk[i], c = sk[ixj];
          bool asc = ((i & kk) == 0);
          if ((a > c) == asc) { sk[i] = c; sk[ixj] = a; }
        }
      }
    }
  }
  __syncthreads();

  // --- derive arrays ---
  for (int r = tid; r < KTOP; r += 1024) {
    uint64_t key = sk[r];
    float score = unmono_f32(~(uint32_t)(key >> 32));
    uint32_t low = (uint32_t)key;
    uint32_t n = low >> 7;
    uint32_t cls = low & 127u;
    uint64_t vball = __ballot(score > 0.0f);
    if (lane == 0) atomicAdd(&nv, (uint32_t)__popcll(vball));
    const float* p = pred + ((size_t)b * NDET + n) * PREDC;
    float x = p[0], y = p[1], w = p[2], h = p[3];
    float hw = __fmul_rn(w, 0.5f), hh = __fmul_rn(h, 0.5f);
    float x1 = __fsub_rn(x, hw), y1 = __fsub_rn(y, hh);
    float x2 = __fadd_rn(x, hw), y2 = __fadd_rn(y, hh);
    float clsf = (float)cls;
    float off = __fmul_rn(clsf, MAXWH);
    size_t o = (size_t)b * KTOP + r;
    s_n[o] = n;
    s_score[o] = score;
    s_clsf[o] = clsf;
    s_box[o * 4 + 0] = x1; s_box[o * 4 + 1] = y1;
    s_box[o * 4 + 2] = x2; s_box[o * 4 + 3] = y2;
    s_obox[o * 4 + 0] = __fadd_rn(x1, off); s_obox[o * 4 + 1] = __fadd_rn(y1, off);
    s_obox[o * 4 + 2] = __fadd_rn(x2, off); s_obox[o * 4 + 3] = __fadd_rn(y2, off);
  }
  __syncthreads();
  if (tid == 0) nvalid[b] = nv;
}

// K5: suppression bitmask. mask[b][i][w] bit t = (j=w*32+t > i) && IoU(off_i,off_j) > 0.45
__global__ void k_mask(const float* __restrict__ s_obox, const uint32_t* __restrict__ nvalid,
                       uint32_t* __restrict__ mask) {
  int gid = blockIdx.x * blockDim.x + threadIdx.x; // BATCH*KTOP*64 threads
  int w = gid & 63;
  int i = (gid >> 6) & (KTOP - 1);
  int b = gid >> 17;
  if (i >= (int)nvalid[b]) return;
  const float* bi = s_obox + ((size_t)b * KTOP + i) * 4;
  float ix1 = bi[0], iy1 = bi[1], ix2 = bi[2], iy2 = bi[3];
  float iarea = __fmul_rn(__fsub_rn(ix2, ix1), __fsub_rn(iy2, iy1));
  uint32_t word = 0;
  int j0 = w * 32;
  for (int t = 0; t < 32; ++t) {
    int j = j0 + t;
    if (j <= i) continue;
    const float* bj = s_obox + ((size_t)b * KTOP + j) * 4;
    float jx1 = bj[0], jy1 = bj[1], jx2 = bj[2], jy2 = bj[3];
    float jarea = __fmul_rn(__fsub_rn(jx2, jx1), __fsub_rn(jy2, jy1));
    float ltx = fmaxf(ix1, jx1), lty = fmaxf(iy1, jy1);
    float rbx = fminf(ix2, jx2), rby = fminf(iy2, jy2);
    float wx = fmaxf(__fsub_rn(rbx, ltx), 0.0f);
    float wy = fmaxf(__fsub_rn(rby, lty), 0.0f);
    float inter = __fmul_rn(wx, wy);
    float denom = __fadd_rn(__fsub_rn(__fadd_rn(iarea, jarea), inter), 1e-7f);
    float iou = __fdiv_rn(inter, denom);
    if (iou > IOU_THR) word |= (1u << t);
  }
  mask[((size_t)b * KTOP + i) * 64 + w] = word;
}

// K6: sequential greedy pass, one wave per batch; lane l owns removed word l.
// ALL buffer state in NAMED registers (round-3 lesson: arrays demoted to
// scratch -> 130us; VGPR_Count=40 was the tell). Group-of-32 keeps the
// cross-lane shfl off the serial chain.
__global__ void k_nms(const uint32_t* __restrict__ mask, const uint32_t* __restrict__ nvalid,
                      uint32_t* __restrict__ supp) {
  int b = blockIdx.x;
  int lane = threadIdx.x; // 64 threads = 1 wave
  int nv = (int)nvalid[b];
  const uint32_t* mbl = mask + (size_t)b * KTOP * 64 + lane;
  uint32_t removed = 0;
#define NMS_LD(i) (((i) < nv) ? mbl[(size_t)(i) * 64] : 0u)
#define DECL_A(d) uint32_t A##d = NMS_LD(d);
  REP32(DECL_A)
  int ngrp = (nv + 31) >> 5;
  for (int g = 0; g < ngrp; ++g) {
    int nb = (g + 1) * 32;
#define LOAD_B(d) uint32_t B##d = NMS_LD(nb + d);
    REP32(LOAD_B)
    uint32_t curw = __shfl(removed, g);
    int base = g * 32;
#define STEP(d) { uint32_t bsh = __shfl(A##d, g); \
    bool alive = ((base + d) < nv) && !((curw >> d) & 1u); \
    curw |= alive ? bsh : 0u; \
    removed |= alive ? A##d : 0u; }
    REP32(STEP)
#define COPY(d) A##d = B##d;
    REP32(COPY)
  }
  supp[b * 64 + lane] = removed;
}

// K7: compact kept rows to output (out must be pre-zeroed).
__global__ void __launch_bounds__(256) k_out(
    const uint32_t* __restrict__ supp, const uint32_t* __restrict__ nvalid,
    const uint32_t* __restrict__ s_n, const float* __restrict__ s_score,
    const float* __restrict__ s_clsf, const float* __restrict__ s_box,
    const float* __restrict__ logits, float* __restrict__ out) {
  __shared__ uint32_t keepw[64];
  __shared__ uint32_t pfx[64];
  int b = blockIdx.x, tid = threadIdx.x;
  int nv = (int)nvalid[b];
  if (tid < 64) {
    uint32_t sw = supp[b * 64 + tid];
    int lo = tid * 32;
    uint32_t vm;
    if (nv >= lo + 32) vm = 0xFFFFFFFFu;
    else if (nv <= lo) vm = 0u;
    else vm = (1u << (nv - lo)) - 1u;
    keepw[tid] = (~sw) & vm;
  }
  __syncthreads();
  if (tid == 0) {
    uint32_t c = 0;
    for (int w = 0; w < 64; ++w) { pfx[w] = c; c += __popc(keepw[w]); }
  }
  __syncthreads();
  for (int r = tid; r < KTOP; r += 256) {
    int w = r >> 5, t = r & 31;
    uint32_t kw = keepw[w];
    if (!((kw >> t) & 1u)) continue;
    uint32_t rank = pfx[w] + (uint32_t)__popc(kw & ((1u << t) - 1u));
    if (rank >= MAXDET) continue;
    size_t o = (size_t)b * KTOP + r;
    float* orow = out + ((size_t)b * MAXDET + rank) * OUTC;
    orow[0] = s_box[o * 4 + 0];
    orow[1] = s_box[o * 4 + 1];
    orow[2] = s_box[o * 4 + 2];
    orow[3] = s_box[o * 4 + 3];
    orow[4] = s_score[o];
    orow[5] = s_clsf[o];
    const float* lrow = logits + ((size_t)b * NDET + s_n[o]) * NCLS;
    for (int c2 = 0; c2 < NCLS; ++c2) orow[6 + c2] = lrow[c2];
  }
}

extern "C" void kernel_launch(void* const* d_in, const int* in_sizes, int n_in,
                              void* d_out, int out_size, void* d_ws, size_t ws_size,
                              hipStream_t stream) {
  const float* pred = (const float*)d_in[0];
  const float* logits = (const float*)d_in[1];
  float* out = (float*)d_out;

  char* ws = (char*)d_ws;
  size_t off = 0;
  auto alloc = [&](size_t bytes) -> void* {
    void* p = ws + off;
    off += (bytes + 255) & ~(size_t)255;
    return p;
  };
  uint64_t* keys  = (uint64_t*)alloc((size_t)BATCH * NDET * 8);
  uint32_t* s_n   = (uint32_t*)alloc((size_t)BATCH * KTOP * 4);
  float*    s_sc  = (float*)alloc((size_t)BATCH * KTOP * 4);
  float*    s_cl  = (float*)alloc((size_t)BATCH * KTOP * 4);
  float*    s_box = (float*)alloc((size_t)BATCH * KTOP * 16);
  float*    s_ob  = (float*)alloc((size_t)BATCH * KTOP * 16);
  uint32_t* nval  = (uint32_t*)alloc((size_t)BATCH * 4);
  uint32_t* mask  = (uint32_t*)alloc((size_t)BATCH * KTOP * 64 * 4);
  uint32_t* suppw = (uint32_t*)alloc((size_t)BATCH * 64 * 4);
  (void)ws_size; (void)in_sizes; (void)n_in;

  hipMemsetAsync(d_out, 0, (size_t)out_size * sizeof(float), stream);

  int total = BATCH * NDET;
  k_keys<<<(total + 255) / 256, 256, 0, stream>>>(pred, keys);
  k_sel<<<BATCH, 1024, 0, stream>>>(keys, pred, s_n, s_sc, s_cl, s_box, s_ob, nval);
  k_mask<<<(BATCH * KTOP * 64) / 256, 256, 0, stream>>>(s_ob, nval, mask);
  k_nms<<<BATCH, 64, 0, stream>>>(mask, nval, suppw);
  k_out<<<BATCH, 256, 0, stream>>>(suppw, nval, s_n, s_sc, s_cl, s_box, logits, out);
}

// Round 5
// 297.384 us; speedup vs baseline: 3.0447x; 1.2508x over previous
//
#include <hip/hip_runtime.h>
#include <stdint.h>

#define BATCH 16
#define NDET 25200
#define NCLS 80
#define PREDC 85
#define KTOP 2048
#define MAXDET 300
#define OUTC 86
#define CONF_THR 0.4f
#define IOU_THR 0.45f
#define MAXWH 4096.0f
#define MROWS (KTOP + 64)       // padded mask rows per batch (unconditional prefetch)
#define NBIN 2048
#define NREP 4
#define INVHI 0xBF800000u       // ~mono(-1.0f): score word of invalid rows

#define REP32(F) F(0)F(1)F(2)F(3)F(4)F(5)F(6)F(7)F(8)F(9)F(10)F(11)F(12)F(13)F(14)F(15)F(16)F(17)F(18)F(19)F(20)F(21)F(22)F(23)F(24)F(25)F(26)F(27)F(28)F(29)F(30)F(31)

// ---- monotone float<->uint mapping (ascending) ----
__device__ __forceinline__ uint32_t mono_f32(float f) {
  uint32_t u = __float_as_uint(f);
  return (u & 0x80000000u) ? ~u : (u | 0x80000000u);
}
__device__ __forceinline__ float unmono_f32(uint32_t m) {
  uint32_t u = (m & 0x80000000u) ? (m & 0x7FFFFFFFu) : ~m;
  return __uint_as_float(u);
}

// K1: per-candidate score/class -> packed 64-bit key + 32-bit score word.
// key = hi<<32 | (n<<7) | cls, hi = ~mono(score). Ascending key == lax.top_k order.
__global__ void k_keys(const float* __restrict__ pred, uint64_t* __restrict__ keys,
                       uint32_t* __restrict__ sw) {
  int idx = blockIdx.x * blockDim.x + threadIdx.x;
  if (idx >= BATCH * NDET) return;
  int n = idx % NDET;
  const float* p = pred + (size_t)idx * PREDC;
  float obj = p[4];
  float score = -1.0f;
  uint32_t cls = 0;
  if (obj > CONF_THR) {
    float best = -1e30f;
    int bc = 0;
    for (int c = 0; c < NCLS; ++c) {
      float s = __fmul_rn(p[5 + c], obj);   // single-rounded, no contraction
      if (s > best) { best = s; bc = c; }   // strict > : first max (argmax)
    }
    if (best > CONF_THR) { score = best; cls = (uint32_t)bc; }
  }
  uint32_t hi = ~mono_f32(score);
  sw[idx] = hi;
  keys[idx] = ((uint64_t)hi << 32) | (uint64_t)(((uint32_t)n << 7) | cls);
}

// K2: fused radix-select (3x11-bit passes on score word, exact tie refine on low
// word) + collect + bitonic sort + derive. One 1024-thread block per batch.
__global__ void __launch_bounds__(1024) k_sel(
    const uint64_t* __restrict__ keys, const uint32_t* __restrict__ sw,
    const float* __restrict__ pred,
    uint32_t* __restrict__ s_n, float* __restrict__ s_score, float* __restrict__ s_clsf,
    float* __restrict__ s_box, float* __restrict__ s_obox, uint32_t* __restrict__ nvalid) {
  __shared__ uint64_t sk[KTOP];            // 16 KB
  __shared__ uint32_t hist[NREP][NBIN];    // 32 KB
  __shared__ uint32_t seg[32];
  __shared__ uint32_t sh_digit, sh_cnt, sh_k;
  __shared__ uint32_t ncol, nv;
  int b = blockIdx.x, tid = threadIdx.x, lane = tid & 63;
  int rep = (tid >> 8) & (NREP - 1);
  const uint64_t* kb = keys + (size_t)b * NDET;
  const uint32_t* swb = sw + (size_t)b * NDET;
  const uint4* sw4 = (const uint4*)swb;    // NDET = 6300*4 exactly, 16B-aligned base
  if (tid == 0) { sh_k = KTOP; ncol = 0; nv = 0; }

#define CLEAR_HIST() { __syncthreads(); \
  for (int i = tid; i < NREP * NBIN; i += 1024) ((uint32_t*)hist)[i] = 0; \
  __syncthreads(); }

  // find digit d with cum<k<=cum+cnt[d]; sets sh_digit, sh_cnt, sh_k -= cum.
#define FIND() { __syncthreads(); \
  for (int t = tid; t < NBIN; t += 1024) \
    hist[0][t] = hist[0][t] + hist[1][t] + hist[2][t] + hist[3][t]; \
  __syncthreads(); \
  if (tid < 32) { uint32_t s_ = 0; \
    for (int i_ = 0; i_ < 64; ++i_) s_ += hist[0][tid * 64 + i_]; \
    seg[tid] = s_; } \
  __syncthreads(); \
  if (tid == 0) { uint32_t k_ = sh_k, cum_ = 0; int S_ = 0; \
    for (; S_ < 31; ++S_) { if (cum_ + seg[S_] >= k_) break; cum_ += seg[S_]; } \
    int d_ = S_ * 64; \
    for (;; ++d_) { if (cum_ + hist[0][d_] >= k_) break; cum_ += hist[0][d_]; } \
    sh_digit = (uint32_t)d_; sh_cnt = hist[0][d_]; sh_k = k_ - cum_; } \
  __syncthreads(); }

  // ---- pass 0: bits [31:21] ----
  CLEAR_HIST();
  {
    uint32_t invc = 0;
#define P0(s) { if ((s) == INVHI) ++invc; else atomicAdd(&hist[rep][(s) >> 21], 1u); }
    for (int i = tid; i < NDET / 4; i += 1024) {
      uint4 v = sw4[i];
      P0(v.x) P0(v.y) P0(v.z) P0(v.w)
    }
    if (invc) atomicAdd(&hist[rep][INVHI >> 21], invc);
  }
  FIND();
  uint32_t d0 = sh_digit;

  // ---- pass 1: bits [20:10] among prefix d0 ----
  CLEAR_HIST();
  {
    uint32_t invc = 0;
#define P1(s) { if ((s) == INVHI) ++invc; \
    else if (((s) >> 21) == d0) atomicAdd(&hist[rep][((s) >> 10) & 0x7FFu], 1u); }
    for (int i = tid; i < NDET / 4; i += 1024) {
      uint4 v = sw4[i];
      P1(v.x) P1(v.y) P1(v.z) P1(v.w)
    }
    if (invc && (INVHI >> 21) == d0) atomicAdd(&hist[rep][(INVHI >> 10) & 0x7FFu], invc);
  }
  FIND();
  uint32_t pref21 = (d0 << 11) | sh_digit;

  // ---- pass 2: bits [9:0] among prefix ----
  CLEAR_HIST();
  {
    uint32_t invc = 0;
#define P2(s) { if ((s) == INVHI) ++invc; \
    else if (((s) >> 10) == pref21) atomicAdd(&hist[rep][(s) & 0x3FFu], 1u); }
    for (int i = tid; i < NDET / 4; i += 1024) {
      uint4 v = sw4[i];
      P2(v.x) P2(v.y) P2(v.z) P2(v.w)
    }
    if (invc && (INVHI >> 10) == pref21) atomicAdd(&hist[rep][INVHI & 0x3FFu], invc);
  }
  FIND();
  uint32_t sstar = (pref21 << 10) | sh_digit;
  uint32_t E = sh_cnt, r = sh_k;           // 1 <= r <= E
  uint32_t Lstar = 0xFFFFFFFFu;

  if (r < E) {
    // exact tie refine: r-th smallest low word (22 bits) among sw==sstar.
    CLEAR_HIST();
    for (int n = tid; n < NDET; n += 1024) {
      uint64_t key = kb[n];
      if ((uint32_t)(key >> 32) == sstar)
        atomicAdd(&hist[rep][((uint32_t)key >> 11) & 0x7FFu], 1u);
    }
    FIND();
    uint32_t dr0 = sh_digit;
    CLEAR_HIST();
    for (int n = tid; n < NDET; n += 1024) {
      uint64_t key = kb[n];
      uint32_t low = (uint32_t)key;
      if ((uint32_t)(key >> 32) == sstar && ((low >> 11) & 0x7FFu) == dr0)
        atomicAdd(&hist[rep][low & 0x7FFu], 1u);
    }
    FIND();
    Lstar = (dr0 << 11) | sh_digit;
  }

  // ---- collect exactly KTOP keys ----
  for (int n = tid; n < NDET; n += 1024) {
    uint64_t key = kb[n];
    uint32_t hi = (uint32_t)(key >> 32);
    bool inc = (hi < sstar) || (hi == sstar && (uint32_t)key <= Lstar);
    uint64_t ball = __ballot(inc);
    uint32_t bse = 0;
    if (lane == 0) bse = atomicAdd(&ncol, (uint32_t)__popcll(ball));
    bse = __shfl(bse, 0);
    if (inc) {
      uint32_t pos = bse + (uint32_t)__popcll(ball & ((1ull << lane) - 1ull));
      if (pos < KTOP) sk[pos] = key;
    }
  }

  // ---- bitonic sort ascending ----
  for (int kk = 2; kk <= KTOP; kk <<= 1) {
    for (int j = kk >> 1; j > 0; j >>= 1) {
      __syncthreads();
      for (int i = tid; i < KTOP; i += 1024) {
        int ixj = i ^ j;
        if (ixj > i) {
          uint64_t a = sk[i], c = sk[ixj];
          bool asc = ((i & kk) == 0);
          if ((a > c) == asc) { sk[i] = c; sk[ixj] = a; }
        }
      }
    }
  }
  __syncthreads();

  // ---- derive arrays ----
  for (int rr = tid; rr < KTOP; rr += 1024) {
    uint64_t key = sk[rr];
    float score = unmono_f32(~(uint32_t)(key >> 32));
    uint32_t low = (uint32_t)key;
    uint32_t n = low >> 7;
    uint32_t cls = low & 127u;
    uint64_t vball = __ballot(score > 0.0f);
    if (lane == 0) atomicAdd(&nv, (uint32_t)__popcll(vball));
    const float* p = pred + ((size_t)b * NDET + n) * PREDC;
    float x = p[0], y = p[1], w = p[2], h = p[3];
    float hw = __fmul_rn(w, 0.5f), hh = __fmul_rn(h, 0.5f);
    float x1 = __fsub_rn(x, hw), y1 = __fsub_rn(y, hh);
    float x2 = __fadd_rn(x, hw), y2 = __fadd_rn(y, hh);
    float clsf = (float)cls;
    float off = __fmul_rn(clsf, MAXWH);
    size_t o = (size_t)b * KTOP + rr;
    s_n[o] = n;
    s_score[o] = score;
    s_clsf[o] = clsf;
    s_box[o * 4 + 0] = x1; s_box[o * 4 + 1] = y1;
    s_box[o * 4 + 2] = x2; s_box[o * 4 + 3] = y2;
    s_obox[o * 4 + 0] = __fadd_rn(x1, off); s_obox[o * 4 + 1] = __fadd_rn(y1, off);
    s_obox[o * 4 + 2] = __fadd_rn(x2, off); s_obox[o * 4 + 3] = __fadd_rn(y2, off);
  }
  __syncthreads();
  if (tid == 0) nvalid[b] = nv;
}

// K5: suppression bitmask. mask[b][i][w] bit t = (j=w*32+t > i) && IoU > 0.45
__global__ void k_mask(const float* __restrict__ s_obox, const uint32_t* __restrict__ nvalid,
                       uint32_t* __restrict__ mask) {
  int gid = blockIdx.x * blockDim.x + threadIdx.x; // BATCH*KTOP*64 threads
  int w = gid & 63;
  int i = (gid >> 6) & (KTOP - 1);
  int b = gid >> 17;
  if (i >= (int)nvalid[b]) return;
  const float* bi = s_obox + ((size_t)b * KTOP + i) * 4;
  float ix1 = bi[0], iy1 = bi[1], ix2 = bi[2], iy2 = bi[3];
  float iarea = __fmul_rn(__fsub_rn(ix2, ix1), __fsub_rn(iy2, iy1));
  uint32_t word = 0;
  int j0 = w * 32;
  for (int t = 0; t < 32; ++t) {
    int j = j0 + t;
    if (j <= i) continue;
    const float* bj = s_obox + ((size_t)b * KTOP + j) * 4;
    float jx1 = bj[0], jy1 = bj[1], jx2 = bj[2], jy2 = bj[3];
    float jarea = __fmul_rn(__fsub_rn(jx2, jx1), __fsub_rn(jy2, jy1));
    float ltx = fmaxf(ix1, jx1), lty = fmaxf(iy1, jy1);
    float rbx = fminf(ix2, jx2), rby = fminf(iy2, jy2);
    float wx = fmaxf(__fsub_rn(rbx, ltx), 0.0f);
    float wy = fmaxf(__fsub_rn(rby, lty), 0.0f);
    float inter = __fmul_rn(wx, wy);
    float denom = __fadd_rn(__fsub_rn(__fadd_rn(iarea, jarea), inter), 1e-7f);
    float iou = __fdiv_rn(inter, denom);
    if (iou > IOU_THR) word |= (1u << t);
  }
  mask[((size_t)b * MROWS + i) * 64 + w] = word;
}

// K6: sequential greedy pass, one wave per batch; lane l owns removed word l.
// Loads are UNCONDITIONAL (padded MROWS buffer; garbage rows gated by `alive`)
// and PINNED via asm so the compiler cannot sink them into the serial chain
// (round-4 lesson: VGPR=40 meant loads rematerialized at use => 152 cyc/row).
__global__ void k_nms(const uint32_t* __restrict__ mask, const uint32_t* __restrict__ nvalid,
                      uint32_t* __restrict__ supp) {
  int b = blockIdx.x;
  int lane = threadIdx.x; // 64 threads = 1 wave
  int nv = (int)nvalid[b];
  const uint32_t* mbl = mask + (size_t)b * MROWS * 64 + lane;
  uint32_t removed = 0;
#define DECL_A(d) uint32_t A##d = mbl[(size_t)(d) * 64];
  REP32(DECL_A)
#define DECL_B(d) uint32_t B##d = mbl[(size_t)(32 + d) * 64];
  REP32(DECL_B)
#define PIN_A(d) asm volatile("" : "+v"(A##d));
  REP32(PIN_A)
#define PIN_B(d) asm volatile("" : "+v"(B##d));
  REP32(PIN_B)
  int ngrp = (nv + 31) >> 5;
  for (int g = 0; g < ngrp; ++g) {
    const uint32_t* pf = mbl + (size_t)(g + 2) * 32 * 64;   // prefetch 2 groups ahead
#define DECL_C(d) uint32_t C##d = pf[(size_t)(d) * 64];
    REP32(DECL_C)
#define PIN_C(d) asm volatile("" : "+v"(C##d));
    REP32(PIN_C)
    uint32_t curw = __shfl(removed, g);
    int base = g * 32;
#define STEP(d) { uint32_t bsh = __shfl(A##d, g); \
    bool alive = ((base + d) < nv) && !((curw >> d) & 1u); \
    curw |= alive ? bsh : 0u; \
    removed |= alive ? A##d : 0u; }
    REP32(STEP)
#define SHIFT(d) A##d = B##d; B##d = C##d;
    REP32(SHIFT)
  }
  supp[b * 64 + lane] = removed;
}

// K7: compact kept rows to output (out pre-zeroed via memset).
__global__ void __launch_bounds__(256) k_out(
    const uint32_t* __restrict__ supp, const uint32_t* __restrict__ nvalid,
    const uint32_t* __restrict__ s_n, const float* __restrict__ s_score,
    const float* __restrict__ s_clsf, const float* __restrict__ s_box,
    const float* __restrict__ logits, float* __restrict__ out) {
  __shared__ uint32_t keepw[64];
  __shared__ uint32_t pfx[64];
  int b = blockIdx.x, tid = threadIdx.x;
  int nv = (int)nvalid[b];
  if (tid < 64) {
    uint32_t sw2 = supp[b * 64 + tid];
    int lo = tid * 32;
    uint32_t vm;
    if (nv >= lo + 32) vm = 0xFFFFFFFFu;
    else if (nv <= lo) vm = 0u;
    else vm = (1u << (nv - lo)) - 1u;
    keepw[tid] = (~sw2) & vm;
  }
  __syncthreads();
  if (tid == 0) {
    uint32_t c = 0;
    for (int w = 0; w < 64; ++w) { pfx[w] = c; c += __popc(keepw[w]); }
  }
  __syncthreads();
  for (int r = tid; r < KTOP; r += 256) {
    int w = r >> 5, t = r & 31;
    uint32_t kw = keepw[w];
    if (!((kw >> t) & 1u)) continue;
    uint32_t rank = pfx[w] + (uint32_t)__popc(kw & ((1u << t) - 1u));
    if (rank >= MAXDET) continue;
    size_t o = (size_t)b * KTOP + r;
    float* orow = out + ((size_t)b * MAXDET + rank) * OUTC;
    orow[0] = s_box[o * 4 + 0];
    orow[1] = s_box[o * 4 + 1];
    orow[2] = s_box[o * 4 + 2];
    orow[3] = s_box[o * 4 + 3];
    orow[4] = s_score[o];
    orow[5] = s_clsf[o];
    const float* lrow = logits + ((size_t)b * NDET + s_n[o]) * NCLS;
    for (int c2 = 0; c2 < NCLS; ++c2) orow[6 + c2] = lrow[c2];
  }
}

extern "C" void kernel_launch(void* const* d_in, const int* in_sizes, int n_in,
                              void* d_out, int out_size, void* d_ws, size_t ws_size,
                              hipStream_t stream) {
  const float* pred = (const float*)d_in[0];
  const float* logits = (const float*)d_in[1];
  float* out = (float*)d_out;

  char* ws = (char*)d_ws;
  size_t off = 0;
  auto alloc = [&](size_t bytes) -> void* {
    void* p = ws + off;
    off += (bytes + 255) & ~(size_t)255;
    return p;
  };
  uint64_t* keys  = (uint64_t*)alloc((size_t)BATCH * NDET * 8);
  uint32_t* sw    = (uint32_t*)alloc((size_t)BATCH * NDET * 4);
  uint32_t* s_n   = (uint32_t*)alloc((size_t)BATCH * KTOP * 4);
  float*    s_sc  = (float*)alloc((size_t)BATCH * KTOP * 4);
  float*    s_cl  = (float*)alloc((size_t)BATCH * KTOP * 4);
  float*    s_box = (float*)alloc((size_t)BATCH * KTOP * 16);
  float*    s_ob  = (float*)alloc((size_t)BATCH * KTOP * 16);
  uint32_t* nval  = (uint32_t*)alloc((size_t)BATCH * 4);
  uint32_t* mask  = (uint32_t*)alloc((size_t)BATCH * MROWS * 64 * 4);
  uint32_t* suppw = (uint32_t*)alloc((size_t)BATCH * 64 * 4);
  (void)ws_size; (void)in_sizes; (void)n_in;

  hipMemsetAsync(d_out, 0, (size_t)out_size * sizeof(float), stream);

  int total = BATCH * NDET;
  k_keys<<<(total + 255) / 256, 256, 0, stream>>>(pred, keys, sw);
  k_sel<<<BATCH, 1024, 0, stream>>>(keys, sw, pred, s_n, s_sc, s_cl, s_box, s_ob, nval);
  k_mask<<<(BATCH * KTOP * 64) / 256, 256, 0, stream>>>(s_ob, nval, mask);
  k_nms<<<BATCH, 64, 0, stream>>>(mask, nval, suppw);
  k_out<<<BATCH, 256, 0, stream>>>(suppw, nval, s_n, s_sc, s_cl, s_box, logits, out);
}

// Round 6
// 248.373 us; speedup vs baseline: 3.6455x; 1.1973x over previous
//
#include <hip/hip_runtime.h>
#include <stdint.h>

#define BATCH 16
#define NDET 25200
#define NCLS 80
#define PREDC 85
#define KTOP 2048
#define MAXDET 300
#define OUTC 86
#define CONF_THR 0.4f
#define IOU_THR 0.45f
#define MAXWH 4096.0f
#define MROWS (KTOP + 64)       // padded mask rows per batch
#define NBIN 2048
#define NREP 4
#define INVHI 0xBF800000u       // ~mono(-1.0f): score word of invalid rows

#define REP32(F) F(0)F(1)F(2)F(3)F(4)F(5)F(6)F(7)F(8)F(9)F(10)F(11)F(12)F(13)F(14)F(15)F(16)F(17)F(18)F(19)F(20)F(21)F(22)F(23)F(24)F(25)F(26)F(27)F(28)F(29)F(30)F(31)

// ---- monotone float<->uint mapping (ascending) ----
__device__ __forceinline__ uint32_t mono_f32(float f) {
  uint32_t u = __float_as_uint(f);
  return (u & 0x80000000u) ? ~u : (u | 0x80000000u);
}
__device__ __forceinline__ float unmono_f32(uint32_t m) {
  uint32_t u = (m & 0x80000000u) ? (m & 0x7FFFFFFFu) : ~m;
  return __uint_as_float(u);
}

// K1: per-candidate score/class -> packed 64-bit key + 32-bit score word.
__global__ void k_keys(const float* __restrict__ pred, uint64_t* __restrict__ keys,
                       uint32_t* __restrict__ sw) {
  int idx = blockIdx.x * blockDim.x + threadIdx.x;
  if (idx >= BATCH * NDET) return;
  int n = idx % NDET;
  const float* p = pred + (size_t)idx * PREDC;
  float obj = p[4];
  float score = -1.0f;
  uint32_t cls = 0;
  if (obj > CONF_THR) {
    float best = -1e30f;
    int bc = 0;
    for (int c = 0; c < NCLS; ++c) {
      float s = __fmul_rn(p[5 + c], obj);   // single-rounded, no contraction
      if (s > best) { best = s; bc = c; }   // strict > : first max (argmax)
    }
    if (best > CONF_THR) { score = best; cls = (uint32_t)bc; }
  }
  uint32_t hi = ~mono_f32(score);
  sw[idx] = hi;
  keys[idx] = ((uint64_t)hi << 32) | (uint64_t)(((uint32_t)n << 7) | cls);
}

// K2: fused radix-select (3x11-bit on score word, exact tie refine) + collect +
// bitonic sort + derive. One 1024-thread block per batch.
__global__ void __launch_bounds__(1024) k_sel(
    const uint64_t* __restrict__ keys, const uint32_t* __restrict__ sw,
    const float* __restrict__ pred,
    uint32_t* __restrict__ s_n, float* __restrict__ s_score, float* __restrict__ s_clsf,
    float* __restrict__ s_box, float* __restrict__ s_obox, uint32_t* __restrict__ nvalid) {
  __shared__ uint64_t sk[KTOP];            // 16 KB
  __shared__ uint32_t hist[NREP][NBIN];    // 32 KB
  __shared__ uint32_t seg[32];
  __shared__ uint32_t sh_digit, sh_cnt, sh_k;
  __shared__ uint32_t ncol, nv;
  int b = blockIdx.x, tid = threadIdx.x, lane = tid & 63;
  int rep = (tid >> 8) & (NREP - 1);
  const uint64_t* kb = keys + (size_t)b * NDET;
  const uint32_t* swb = sw + (size_t)b * NDET;
  const uint4* sw4 = (const uint4*)swb;
  if (tid == 0) { sh_k = KTOP; ncol = 0; nv = 0; }

#define CLEAR_HIST() { __syncthreads(); \
  for (int i = tid; i < NREP * NBIN; i += 1024) ((uint32_t*)hist)[i] = 0; \
  __syncthreads(); }

#define FIND() { __syncthreads(); \
  for (int t = tid; t < NBIN; t += 1024) \
    hist[0][t] = hist[0][t] + hist[1][t] + hist[2][t] + hist[3][t]; \
  __syncthreads(); \
  if (tid < 32) { uint32_t s_ = 0; \
    for (int i_ = 0; i_ < 64; ++i_) s_ += hist[0][tid * 64 + i_]; \
    seg[tid] = s_; } \
  __syncthreads(); \
  if (tid == 0) { uint32_t k_ = sh_k, cum_ = 0; int S_ = 0; \
    for (; S_ < 31; ++S_) { if (cum_ + seg[S_] >= k_) break; cum_ += seg[S_]; } \
    int d_ = S_ * 64; \
    for (;; ++d_) { if (cum_ + hist[0][d_] >= k_) break; cum_ += hist[0][d_]; } \
    sh_digit = (uint32_t)d_; sh_cnt = hist[0][d_]; sh_k = k_ - cum_; } \
  __syncthreads(); }

  // ---- pass 0: bits [31:21] ----
  CLEAR_HIST();
  {
    uint32_t invc = 0;
#define P0(s) { if ((s) == INVHI) ++invc; else atomicAdd(&hist[rep][(s) >> 21], 1u); }
    for (int i = tid; i < NDET / 4; i += 1024) {
      uint4 v = sw4[i];
      P0(v.x) P0(v.y) P0(v.z) P0(v.w)
    }
    if (invc) atomicAdd(&hist[rep][INVHI >> 21], invc);
  }
  FIND();
  uint32_t d0 = sh_digit;

  // ---- pass 1: bits [20:10] among prefix d0 ----
  CLEAR_HIST();
  {
    uint32_t invc = 0;
#define P1(s) { if ((s) == INVHI) ++invc; \
    else if (((s) >> 21) == d0) atomicAdd(&hist[rep][((s) >> 10) & 0x7FFu], 1u); }
    for (int i = tid; i < NDET / 4; i += 1024) {
      uint4 v = sw4[i];
      P1(v.x) P1(v.y) P1(v.z) P1(v.w)
    }
    if (invc && (INVHI >> 21) == d0) atomicAdd(&hist[rep][(INVHI >> 10) & 0x7FFu], invc);
  }
  FIND();
  uint32_t pref21 = (d0 << 11) | sh_digit;

  // ---- pass 2: bits [9:0] among prefix ----
  CLEAR_HIST();
  {
    uint32_t invc = 0;
#define P2(s) { if ((s) == INVHI) ++invc; \
    else if (((s) >> 10) == pref21) atomicAdd(&hist[rep][(s) & 0x3FFu], 1u); }
    for (int i = tid; i < NDET / 4; i += 1024) {
      uint4 v = sw4[i];
      P2(v.x) P2(v.y) P2(v.z) P2(v.w)
    }
    if (invc && (INVHI >> 10) == pref21) atomicAdd(&hist[rep][INVHI & 0x3FFu], invc);
  }
  FIND();
  uint32_t sstar = (pref21 << 10) | sh_digit;
  uint32_t E = sh_cnt, r = sh_k;           // 1 <= r <= E
  uint32_t Lstar = 0xFFFFFFFFu;

  if (r < E) {
    // exact tie refine: r-th smallest low word (22 bits) among sw==sstar.
    CLEAR_HIST();
    for (int n = tid; n < NDET; n += 1024) {
      uint64_t key = kb[n];
      if ((uint32_t)(key >> 32) == sstar)
        atomicAdd(&hist[rep][((uint32_t)key >> 11) & 0x7FFu], 1u);
    }
    FIND();
    uint32_t dr0 = sh_digit;
    CLEAR_HIST();
    for (int n = tid; n < NDET; n += 1024) {
      uint64_t key = kb[n];
      uint32_t low = (uint32_t)key;
      if ((uint32_t)(key >> 32) == sstar && ((low >> 11) & 0x7FFu) == dr0)
        atomicAdd(&hist[rep][low & 0x7FFu], 1u);
    }
    FIND();
    Lstar = (dr0 << 11) | sh_digit;
  }

  // ---- collect exactly KTOP keys ----
  for (int n = tid; n < NDET; n += 1024) {
    uint64_t key = kb[n];
    uint32_t hi = (uint32_t)(key >> 32);
    bool inc = (hi < sstar) || (hi == sstar && (uint32_t)key <= Lstar);
    uint64_t ball = __ballot(inc);
    uint32_t bse = 0;
    if (lane == 0) bse = atomicAdd(&ncol, (uint32_t)__popcll(ball));
    bse = __shfl(bse, 0);
    if (inc) {
      uint32_t pos = bse + (uint32_t)__popcll(ball & ((1ull << lane) - 1ull));
      if (pos < KTOP) sk[pos] = key;
    }
  }

  // ---- bitonic sort ascending ----
  for (int kk = 2; kk <= KTOP; kk <<= 1) {
    for (int j = kk >> 1; j > 0; j >>= 1) {
      __syncthreads();
      for (int i = tid; i < KTOP; i += 1024) {
        int ixj = i ^ j;
        if (ixj > i) {
          uint64_t a = sk[i], c = sk[ixj];
          bool asc = ((i & kk) == 0);
          if ((a > c) == asc) { sk[i] = c; sk[ixj] = a; }
        }
      }
    }
  }
  __syncthreads();

  // ---- derive arrays ----
  for (int rr = tid; rr < KTOP; rr += 1024) {
    uint64_t key = sk[rr];
    float score = unmono_f32(~(uint32_t)(key >> 32));
    uint32_t low = (uint32_t)key;
    uint32_t n = low >> 7;
    uint32_t cls = low & 127u;
    uint64_t vball = __ballot(score > 0.0f);
    if (lane == 0) atomicAdd(&nv, (uint32_t)__popcll(vball));
    const float* p = pred + ((size_t)b * NDET + n) * PREDC;
    float x = p[0], y = p[1], w = p[2], h = p[3];
    float hw = __fmul_rn(w, 0.5f), hh = __fmul_rn(h, 0.5f);
    float x1 = __fsub_rn(x, hw), y1 = __fsub_rn(y, hh);
    float x2 = __fadd_rn(x, hw), y2 = __fadd_rn(y, hh);
    float clsf = (float)cls;
    float off = __fmul_rn(clsf, MAXWH);
    size_t o = (size_t)b * KTOP + rr;
    s_n[o] = n;
    s_score[o] = score;
    s_clsf[o] = clsf;
    s_box[o * 4 + 0] = x1; s_box[o * 4 + 1] = y1;
    s_box[o * 4 + 2] = x2; s_box[o * 4 + 3] = y2;
    s_obox[o * 4 + 0] = __fadd_rn(x1, off); s_obox[o * 4 + 1] = __fadd_rn(y1, off);
    s_obox[o * 4 + 2] = __fadd_rn(x2, off); s_obox[o * 4 + 3] = __fadd_rn(y2, off);
  }
  __syncthreads();
  if (tid == 0) nvalid[b] = nv;
}

// K5: suppression bitmask + diagonal-block side buffer.
// mask[b][i][w] bit t = (j=w*32+t > i) && IoU > 0.45; diag[b][i] = mask[b][i][i>>5].
__global__ void k_mask(const float* __restrict__ s_obox, const uint32_t* __restrict__ nvalid,
                       uint32_t* __restrict__ mask, uint32_t* __restrict__ diag) {
  int gid = blockIdx.x * blockDim.x + threadIdx.x; // BATCH*KTOP*64 threads
  int w = gid & 63;
  int i = (gid >> 6) & (KTOP - 1);
  int b = gid >> 17;
  if (i >= (int)nvalid[b]) return;
  const float* bi = s_obox + ((size_t)b * KTOP + i) * 4;
  float ix1 = bi[0], iy1 = bi[1], ix2 = bi[2], iy2 = bi[3];
  float iarea = __fmul_rn(__fsub_rn(ix2, ix1), __fsub_rn(iy2, iy1));
  uint32_t word = 0;
  int j0 = w * 32;
  for (int t = 0; t < 32; ++t) {
    int j = j0 + t;
    if (j <= i) continue;
    const float* bj = s_obox + ((size_t)b * KTOP + j) * 4;
    float jx1 = bj[0], jy1 = bj[1], jx2 = bj[2], jy2 = bj[3];
    float jarea = __fmul_rn(__fsub_rn(jx2, jx1), __fsub_rn(jy2, jy1));
    float ltx = fmaxf(ix1, jx1), lty = fmaxf(iy1, jy1);
    float rbx = fminf(ix2, jx2), rby = fminf(iy2, jy2);
    float wx = fmaxf(__fsub_rn(rbx, ltx), 0.0f);
    float wy = fmaxf(__fsub_rn(rby, lty), 0.0f);
    float inter = __fmul_rn(wx, wy);
    float denom = __fadd_rn(__fsub_rn(__fadd_rn(iarea, jarea), inter), 1e-7f);
    float iou = __fdiv_rn(inter, denom);
    if (iou > IOU_THR) word |= (1u << t);
  }
  mask[((size_t)b * MROWS + i) * 64 + w] = word;
  if (w == (i >> 5)) diag[(size_t)b * KTOP + i] = word;
}

// K6: sequential greedy pass, one wave per batch; lane l owns removed word l.
// Serial chain touches ONLY LDS-resident diagonal words (pre-gated into regs);
// full-row OR application is off-chain from batch-issued global loads.
// launch_bounds(64,1): round-5 lesson — default reg budget (VGPR=52) spilled
// the 96 pinned values to scratch; 1 wave/EU unlocks the full VGPR file.
__global__ void __launch_bounds__(64, 1) k_nms(
    const uint32_t* __restrict__ mask, const uint32_t* __restrict__ diag,
    const uint32_t* __restrict__ nvalid, uint32_t* __restrict__ supp) {
  __shared__ uint32_t ldsd[KTOP];
  int b = blockIdx.x;
  int lane = threadIdx.x; // 64 threads = 1 wave
  int nv = (int)nvalid[b];
  const uint32_t* mbl = mask + (size_t)b * MROWS * 64 + lane;
  const uint32_t* db = diag + (size_t)b * KTOP;
  for (int i = lane; i < KTOP; i += 64) ldsd[i] = db[i];
  __syncthreads();
  uint32_t removed = 0;
  int ngrp = (nv + 31) >> 5;
  for (int g = 0; g < ngrp; ++g) {
    int base = g * 32;
    int rem = nv - base;
    uint32_t vm = (rem >= 32) ? 0xFFFFFFFFu : ((1u << rem) - 1u);
    const uint32_t* rp = mbl + (size_t)base * 64;
    // issue full-row loads early (used only after the chain, ~450 cy later)
#define DECL_R(d) uint32_t R##d = rp[(size_t)(d) * 64];
    REP32(DECL_R)
#define PIN_R(d) asm volatile("" : "+v"(R##d));
    REP32(PIN_R)
    // pre-gated diag words from LDS (broadcast reads, off-chain)
#define DECL_S(d) uint32_t S##d = ldsd[base + d] & ((uint32_t)0 - ((vm >> d) & 1u));
    REP32(DECL_S)
    uint32_t curw = __shfl(removed, g);
    uint32_t cinit = curw;
    // serial chain: step d ORs only bits > d, so bit d is final before step d.
#define CHAIN(d) { uint32_t m_ = ((curw >> d) & 1u) - 1u; curw |= m_ & S##d; }
    REP32(CHAIN)
    uint32_t am = vm & ~(curw | cinit);
    // apply alive rows (off the serial chain, OR-tree reassociable)
#define APPLY(d) removed |= R##d & ((uint32_t)0 - ((am >> d) & 1u));
    REP32(APPLY)
  }
  supp[b * 64 + lane] = removed;
}

// K7: compact kept rows to output (out pre-zeroed via memset).
__global__ void __launch_bounds__(256) k_out(
    const uint32_t* __restrict__ supp, const uint32_t* __restrict__ nvalid,
    const uint32_t* __restrict__ s_n, const float* __restrict__ s_score,
    const float* __restrict__ s_clsf, const float* __restrict__ s_box,
    const float* __restrict__ logits, float* __restrict__ out) {
  __shared__ uint32_t keepw[64];
  __shared__ uint32_t pfx[64];
  int b = blockIdx.x, tid = threadIdx.x;
  int nv = (int)nvalid[b];
  if (tid < 64) {
    uint32_t sw2 = supp[b * 64 + tid];
    int lo = tid * 32;
    uint32_t vm;
    if (nv >= lo + 32) vm = 0xFFFFFFFFu;
    else if (nv <= lo) vm = 0u;
    else vm = (1u << (nv - lo)) - 1u;
    keepw[tid] = (~sw2) & vm;
  }
  __syncthreads();
  if (tid == 0) {
    uint32_t c = 0;
    for (int w = 0; w < 64; ++w) { pfx[w] = c; c += __popc(keepw[w]); }
  }
  __syncthreads();
  for (int r = tid; r < KTOP; r += 256) {
    int w = r >> 5, t = r & 31;
    uint32_t kw = keepw[w];
    if (!((kw >> t) & 1u)) continue;
    uint32_t rank = pfx[w] + (uint32_t)__popc(kw & ((1u << t) - 1u));
    if (rank >= MAXDET) continue;
    size_t o = (size_t)b * KTOP + r;
    float* orow = out + ((size_t)b * MAXDET + rank) * OUTC;
    orow[0] = s_box[o * 4 + 0];
    orow[1] = s_box[o * 4 + 1];
    orow[2] = s_box[o * 4 + 2];
    orow[3] = s_box[o * 4 + 3];
    orow[4] = s_score[o];
    orow[5] = s_clsf[o];
    const float* lrow = logits + ((size_t)b * NDET + s_n[o]) * NCLS;
    for (int c2 = 0; c2 < NCLS; ++c2) orow[6 + c2] = lrow[c2];
  }
}

extern "C" void kernel_launch(void* const* d_in, const int* in_sizes, int n_in,
                              void* d_out, int out_size, void* d_ws, size_t ws_size,
                              hipStream_t stream) {
  const float* pred = (const float*)d_in[0];
  const float* logits = (const float*)d_in[1];
  float* out = (float*)d_out;

  char* ws = (char*)d_ws;
  size_t off = 0;
  auto alloc = [&](size_t bytes) -> void* {
    void* p = ws + off;
    off += (bytes + 255) & ~(size_t)255;
    return p;
  };
  uint64_t* keys  = (uint64_t*)alloc((size_t)BATCH * NDET * 8);
  uint32_t* sw    = (uint32_t*)alloc((size_t)BATCH * NDET * 4);
  uint32_t* s_n   = (uint32_t*)alloc((size_t)BATCH * KTOP * 4);
  float*    s_sc  = (float*)alloc((size_t)BATCH * KTOP * 4);
  float*    s_cl  = (float*)alloc((size_t)BATCH * KTOP * 4);
  float*    s_box = (float*)alloc((size_t)BATCH * KTOP * 16);
  float*    s_ob  = (float*)alloc((size_t)BATCH * KTOP * 16);
  uint32_t* nval  = (uint32_t*)alloc((size_t)BATCH * 4);
  uint32_t* mask  = (uint32_t*)alloc((size_t)BATCH * MROWS * 64 * 4);
  uint32_t* diag  = (uint32_t*)alloc((size_t)BATCH * KTOP * 4);
  uint32_t* suppw = (uint32_t*)alloc((size_t)BATCH * 64 * 4);
  (void)ws_size; (void)in_sizes; (void)n_in;

  hipMemsetAsync(d_out, 0, (size_t)out_size * sizeof(float), stream);

  int total = BATCH * NDET;
  k_keys<<<(total + 255) / 256, 256, 0, stream>>>(pred, keys, sw);
  k_sel<<<BATCH, 1024, 0, stream>>>(keys, sw, pred, s_n, s_sc, s_cl, s_box, s_ob, nval);
  k_mask<<<(BATCH * KTOP * 64) / 256, 256, 0, stream>>>(s_ob, nval, mask, diag);
  k_nms<<<BATCH, 64, 0, stream>>>(mask, diag, nval, suppw);
  k_out<<<BATCH, 256, 0, stream>>>(suppw, nval, s_n, s_sc, s_cl, s_box, logits, out);
}

// Round 7
// 177.582 us; speedup vs baseline: 5.0987x; 1.3986x over previous
//
#include <hip/hip_runtime.h>
#include <stdint.h>

#define BATCH 16
#define NDET 25200
#define NCLS 80
#define PREDC 85
#define KTOP 2048
#define MAXDET 300
#define OUTC 86
#define CONF_THR 0.4f
#define IOU_THR 0.45f
#define MAXWH 4096.0f
#define MROWS (KTOP + 64)       // padded mask rows per batch
#define NBIN 2048
#define NREP 4
#define INVHI 0xBF800000u       // ~mono(-1.0f): score word of invalid rows
#define BMW (NCLS * 64)         // class bitmap words per batch (80 classes x 64)

#define REP32(F) F(0)F(1)F(2)F(3)F(4)F(5)F(6)F(7)F(8)F(9)F(10)F(11)F(12)F(13)F(14)F(15)F(16)F(17)F(18)F(19)F(20)F(21)F(22)F(23)F(24)F(25)F(26)F(27)F(28)F(29)F(30)F(31)

// ---- monotone float<->uint mapping (ascending) ----
__device__ __forceinline__ uint32_t mono_f32(float f) {
  uint32_t u = __float_as_uint(f);
  return (u & 0x80000000u) ? ~u : (u | 0x80000000u);
}
__device__ __forceinline__ float unmono_f32(uint32_t m) {
  uint32_t u = (m & 0x80000000u) ? (m & 0x7FFFFFFFu) : ~m;
  return __uint_as_float(u);
}

// K1: per-candidate score/class -> packed 64-bit key + 32-bit score word.
__global__ void k_keys(const float* __restrict__ pred, uint64_t* __restrict__ keys,
                       uint32_t* __restrict__ sw) {
  int idx = blockIdx.x * blockDim.x + threadIdx.x;
  if (idx >= BATCH * NDET) return;
  int n = idx % NDET;
  const float* p = pred + (size_t)idx * PREDC;
  float obj = p[4];
  float score = -1.0f;
  uint32_t cls = 0;
  if (obj > CONF_THR) {
    float best = -1e30f;
    int bc = 0;
    for (int c = 0; c < NCLS; ++c) {
      float s = __fmul_rn(p[5 + c], obj);   // single-rounded, no contraction
      if (s > best) { best = s; bc = c; }   // strict > : first max (argmax)
    }
    if (best > CONF_THR) { score = best; cls = (uint32_t)bc; }
  }
  uint32_t hi = ~mono_f32(score);
  sw[idx] = hi;
  keys[idx] = ((uint64_t)hi << 32) | (uint64_t)(((uint32_t)n << 7) | cls);
}

// K2: fused radix-select (3x11-bit on score word, exact tie refine) + collect +
// bitonic sort + derive (+ integer class array + per-class rank bitmap).
// One 1024-thread block per batch.
__global__ void __launch_bounds__(1024) k_sel(
    const uint64_t* __restrict__ keys, const uint32_t* __restrict__ sw,
    const float* __restrict__ pred,
    uint32_t* __restrict__ s_n, float* __restrict__ s_score, float* __restrict__ s_clsf,
    uint32_t* __restrict__ s_cli, uint32_t* __restrict__ clsbm,
    float* __restrict__ s_box, float* __restrict__ s_obox, uint32_t* __restrict__ nvalid) {
  __shared__ uint64_t sk[KTOP];            // 16 KB
  __shared__ uint32_t hist[NREP][NBIN];    // 32 KB (reused as class bitmap later)
  __shared__ uint32_t seg[32];
  __shared__ uint32_t sh_digit, sh_cnt, sh_k;
  __shared__ uint32_t ncol, nv;
  int b = blockIdx.x, tid = threadIdx.x, lane = tid & 63;
  int rep = (tid >> 8) & (NREP - 1);
  const uint64_t* kb = keys + (size_t)b * NDET;
  const uint32_t* swb = sw + (size_t)b * NDET;
  const uint4* sw4 = (const uint4*)swb;
  if (tid == 0) { sh_k = KTOP; ncol = 0; nv = 0; }

#define CLEAR_HIST() { __syncthreads(); \
  for (int i = tid; i < NREP * NBIN; i += 1024) ((uint32_t*)hist)[i] = 0; \
  __syncthreads(); }

#define FIND() { __syncthreads(); \
  for (int t = tid; t < NBIN; t += 1024) \
    hist[0][t] = hist[0][t] + hist[1][t] + hist[2][t] + hist[3][t]; \
  __syncthreads(); \
  if (tid < 32) { uint32_t s_ = 0; \
    for (int i_ = 0; i_ < 64; ++i_) s_ += hist[0][tid * 64 + i_]; \
    seg[tid] = s_; } \
  __syncthreads(); \
  if (tid == 0) { uint32_t k_ = sh_k, cum_ = 0; int S_ = 0; \
    for (; S_ < 31; ++S_) { if (cum_ + seg[S_] >= k_) break; cum_ += seg[S_]; } \
    int d_ = S_ * 64; \
    for (;; ++d_) { if (cum_ + hist[0][d_] >= k_) break; cum_ += hist[0][d_]; } \
    sh_digit = (uint32_t)d_; sh_cnt = hist[0][d_]; sh_k = k_ - cum_; } \
  __syncthreads(); }

  // ---- pass 0: bits [31:21] ----
  CLEAR_HIST();
  {
    uint32_t invc = 0;
#define P0(s) { if ((s) == INVHI) ++invc; else atomicAdd(&hist[rep][(s) >> 21], 1u); }
    for (int i = tid; i < NDET / 4; i += 1024) {
      uint4 v = sw4[i];
      P0(v.x) P0(v.y) P0(v.z) P0(v.w)
    }
    if (invc) atomicAdd(&hist[rep][INVHI >> 21], invc);
  }
  FIND();
  uint32_t d0 = sh_digit;

  // ---- pass 1: bits [20:10] among prefix d0 ----
  CLEAR_HIST();
  {
    uint32_t invc = 0;
#define P1(s) { if ((s) == INVHI) ++invc; \
    else if (((s) >> 21) == d0) atomicAdd(&hist[rep][((s) >> 10) & 0x7FFu], 1u); }
    for (int i = tid; i < NDET / 4; i += 1024) {
      uint4 v = sw4[i];
      P1(v.x) P1(v.y) P1(v.z) P1(v.w)
    }
    if (invc && (INVHI >> 21) == d0) atomicAdd(&hist[rep][(INVHI >> 10) & 0x7FFu], invc);
  }
  FIND();
  uint32_t pref21 = (d0 << 11) | sh_digit;

  // ---- pass 2: bits [9:0] among prefix ----
  CLEAR_HIST();
  {
    uint32_t invc = 0;
#define P2(s) { if ((s) == INVHI) ++invc; \
    else if (((s) >> 10) == pref21) atomicAdd(&hist[rep][(s) & 0x3FFu], 1u); }
    for (int i = tid; i < NDET / 4; i += 1024) {
      uint4 v = sw4[i];
      P2(v.x) P2(v.y) P2(v.z) P2(v.w)
    }
    if (invc && (INVHI >> 10) == pref21) atomicAdd(&hist[rep][INVHI & 0x3FFu], invc);
  }
  FIND();
  uint32_t sstar = (pref21 << 10) | sh_digit;
  uint32_t E = sh_cnt, r = sh_k;           // 1 <= r <= E
  uint32_t Lstar = 0xFFFFFFFFu;

  if (r < E) {
    // exact tie refine: r-th smallest low word (22 bits) among sw==sstar.
    CLEAR_HIST();
    for (int n = tid; n < NDET; n += 1024) {
      uint64_t key = kb[n];
      if ((uint32_t)(key >> 32) == sstar)
        atomicAdd(&hist[rep][((uint32_t)key >> 11) & 0x7FFu], 1u);
    }
    FIND();
    uint32_t dr0 = sh_digit;
    CLEAR_HIST();
    for (int n = tid; n < NDET; n += 1024) {
      uint64_t key = kb[n];
      uint32_t low = (uint32_t)key;
      if ((uint32_t)(key >> 32) == sstar && ((low >> 11) & 0x7FFu) == dr0)
        atomicAdd(&hist[rep][low & 0x7FFu], 1u);
    }
    FIND();
    Lstar = (dr0 << 11) | sh_digit;
  }

  // ---- collect exactly KTOP keys ----
  for (int n = tid; n < NDET; n += 1024) {
    uint64_t key = kb[n];
    uint32_t hi = (uint32_t)(key >> 32);
    bool inc = (hi < sstar) || (hi == sstar && (uint32_t)key <= Lstar);
    uint64_t ball = __ballot(inc);
    uint32_t bse = 0;
    if (lane == 0) bse = atomicAdd(&ncol, (uint32_t)__popcll(ball));
    bse = __shfl(bse, 0);
    if (inc) {
      uint32_t pos = bse + (uint32_t)__popcll(ball & ((1ull << lane) - 1ull));
      if (pos < KTOP) sk[pos] = key;
    }
  }

  // ---- bitonic sort ascending ----
  for (int kk = 2; kk <= KTOP; kk <<= 1) {
    for (int j = kk >> 1; j > 0; j >>= 1) {
      __syncthreads();
      for (int i = tid; i < KTOP; i += 1024) {
        int ixj = i ^ j;
        if (ixj > i) {
          uint64_t a = sk[i], c = sk[ixj];
          bool asc = ((i & kk) == 0);
          if ((a > c) == asc) { sk[i] = c; sk[ixj] = a; }
        }
      }
    }
  }
  __syncthreads();

  // ---- class bitmap (reuse hist space; all hist uses are done) ----
  uint32_t* bm = (uint32_t*)hist;          // BMW = 5120 words <= 8192
  for (int i = tid; i < BMW; i += 1024) bm[i] = 0;
  __syncthreads();

  // ---- derive arrays ----
  for (int rr = tid; rr < KTOP; rr += 1024) {
    uint64_t key = sk[rr];
    float score = unmono_f32(~(uint32_t)(key >> 32));
    uint32_t low = (uint32_t)key;
    uint32_t n = low >> 7;
    uint32_t cls = low & 127u;
    uint64_t vball = __ballot(score > 0.0f);
    if (lane == 0) atomicAdd(&nv, (uint32_t)__popcll(vball));
    if (score > 0.0f) atomicOr(&bm[cls * 64 + (rr >> 5)], 1u << (rr & 31));
    const float* p = pred + ((size_t)b * NDET + n) * PREDC;
    float x = p[0], y = p[1], w = p[2], h = p[3];
    float hw = __fmul_rn(w, 0.5f), hh = __fmul_rn(h, 0.5f);
    float x1 = __fsub_rn(x, hw), y1 = __fsub_rn(y, hh);
    float x2 = __fadd_rn(x, hw), y2 = __fadd_rn(y, hh);
    float clsf = (float)cls;
    float off = __fmul_rn(clsf, MAXWH);
    size_t o = (size_t)b * KTOP + rr;
    s_n[o] = n;
    s_score[o] = score;
    s_clsf[o] = clsf;
    s_cli[o] = cls;
    s_box[o * 4 + 0] = x1; s_box[o * 4 + 1] = y1;
    s_box[o * 4 + 2] = x2; s_box[o * 4 + 3] = y2;
    s_obox[o * 4 + 0] = __fadd_rn(x1, off); s_obox[o * 4 + 1] = __fadd_rn(y1, off);
    s_obox[o * 4 + 2] = __fadd_rn(x2, off); s_obox[o * 4 + 3] = __fadd_rn(y2, off);
  }
  __syncthreads();
  for (int i = tid; i < BMW; i += 1024) clsbm[(size_t)b * BMW + i] = bm[i];
  if (tid == 0) nvalid[b] = nv;
}

// K5: suppression bitmask via per-class rank bitmap.
// Cross-class pairs have inter==0 exactly (offset >= 4096-702 apart) so
// iou==0 !> 0.45 — only same-class bits can be set. IoU expression on the
// offset boxes is IDENTICAL to the dense version (bit-exact decisions).
__global__ void k_mask(const float* __restrict__ s_obox, const uint32_t* __restrict__ s_cli,
                       const uint32_t* __restrict__ clsbm, const uint32_t* __restrict__ nvalid,
                       uint32_t* __restrict__ mask, uint32_t* __restrict__ diag) {
  int gid = blockIdx.x * blockDim.x + threadIdx.x; // BATCH*KTOP*64 threads
  int w = gid & 63;
  int i = (gid >> 6) & (KTOP - 1);
  int b = gid >> 17;
  if (i >= (int)nvalid[b]) return;
  int iw = i >> 5, ib = i & 31;
  uint32_t word = 0;
  if (w >= iw) {
    uint32_t ci = s_cli[(size_t)b * KTOP + i];
    uint32_t bmw = clsbm[(size_t)b * BMW + ci * 64 + w];
    uint32_t uptri = (w > iw) ? 0xFFFFFFFFu : ((ib == 31) ? 0u : (0xFFFFFFFFu << (ib + 1)));
    uint32_t mbits = bmw & uptri;
    if (mbits) {
      const float* bi = s_obox + ((size_t)b * KTOP + i) * 4;
      float ix1 = bi[0], iy1 = bi[1], ix2 = bi[2], iy2 = bi[3];
      float iarea = __fmul_rn(__fsub_rn(ix2, ix1), __fsub_rn(iy2, iy1));
      int j0 = w * 32;
      do {
        int t = __ffs(mbits) - 1;
        mbits &= mbits - 1;
        int j = j0 + t;
        const float* bj = s_obox + ((size_t)b * KTOP + j) * 4;
        float jx1 = bj[0], jy1 = bj[1], jx2 = bj[2], jy2 = bj[3];
        float jarea = __fmul_rn(__fsub_rn(jx2, jx1), __fsub_rn(jy2, jy1));
        float ltx = fmaxf(ix1, jx1), lty = fmaxf(iy1, jy1);
        float rbx = fminf(ix2, jx2), rby = fminf(iy2, jy2);
        float wx = fmaxf(__fsub_rn(rbx, ltx), 0.0f);
        float wy = fmaxf(__fsub_rn(rby, lty), 0.0f);
        float inter = __fmul_rn(wx, wy);
        float denom = __fadd_rn(__fsub_rn(__fadd_rn(iarea, jarea), inter), 1e-7f);
        float iou = __fdiv_rn(inter, denom);
        if (iou > IOU_THR) word |= (1u << t);
      } while (mbits);
    }
  }
  mask[((size_t)b * MROWS + i) * 64 + w] = word;
  if (w == iw) diag[(size_t)b * KTOP + i] = word;
}

// K6: sequential greedy pass, one wave per batch; lane l owns removed word l.
// Serial chain touches ONLY LDS-resident diagonal words; full-row OR
// application is off-chain from batch-issued pinned global loads.
__global__ void __launch_bounds__(64, 1) k_nms(
    const uint32_t* __restrict__ mask, const uint32_t* __restrict__ diag,
    const uint32_t* __restrict__ nvalid, uint32_t* __restrict__ supp) {
  __shared__ uint32_t ldsd[KTOP];
  int b = blockIdx.x;
  int lane = threadIdx.x; // 64 threads = 1 wave
  int nv = (int)nvalid[b];
  const uint32_t* mbl = mask + (size_t)b * MROWS * 64 + lane;
  const uint32_t* db = diag + (size_t)b * KTOP;
  for (int i = lane; i < KTOP; i += 64) ldsd[i] = db[i];
  __syncthreads();
  uint32_t removed = 0;
  int ngrp = (nv + 31) >> 5;
  for (int g = 0; g < ngrp; ++g) {
    int base = g * 32;
    int rem = nv - base;
    uint32_t vm = (rem >= 32) ? 0xFFFFFFFFu : ((1u << rem) - 1u);
    const uint32_t* rp = mbl + (size_t)base * 64;
#define DECL_R(d) uint32_t R##d = rp[(size_t)(d) * 64];
    REP32(DECL_R)
#define PIN_R(d) asm volatile("" : "+v"(R##d));
    REP32(PIN_R)
#define DECL_S(d) uint32_t S##d = ldsd[base + d] & ((uint32_t)0 - ((vm >> d) & 1u));
    REP32(DECL_S)
    uint32_t curw = __shfl(removed, g);
    uint32_t cinit = curw;
#define CHAIN(d) { uint32_t m_ = ((curw >> d) & 1u) - 1u; curw |= m_ & S##d; }
    REP32(CHAIN)
    uint32_t am = vm & ~(curw | cinit);
#define APPLY(d) removed |= R##d & ((uint32_t)0 - ((am >> d) & 1u));
    REP32(APPLY)
  }
  supp[b * 64 + lane] = removed;
}

// K7: compact kept rows to output (out pre-zeroed via memset).
__global__ void __launch_bounds__(256) k_out(
    const uint32_t* __restrict__ supp, const uint32_t* __restrict__ nvalid,
    const uint32_t* __restrict__ s_n, const float* __restrict__ s_score,
    const float* __restrict__ s_clsf, const float* __restrict__ s_box,
    const float* __restrict__ logits, float* __restrict__ out) {
  __shared__ uint32_t keepw[64];
  __shared__ uint32_t pfx[64];
  int b = blockIdx.x, tid = threadIdx.x;
  int nv = (int)nvalid[b];
  if (tid < 64) {
    uint32_t sw2 = supp[b * 64 + tid];
    int lo = tid * 32;
    uint32_t vm;
    if (nv >= lo + 32) vm = 0xFFFFFFFFu;
    else if (nv <= lo) vm = 0u;
    else vm = (1u << (nv - lo)) - 1u;
    keepw[tid] = (~sw2) & vm;
  }
  __syncthreads();
  if (tid == 0) {
    uint32_t c = 0;
    for (int w = 0; w < 64; ++w) { pfx[w] = c; c += __popc(keepw[w]); }
  }
  __syncthreads();
  for (int r = tid; r < KTOP; r += 256) {
    int w = r >> 5, t = r & 31;
    uint32_t kw = keepw[w];
    if (!((kw >> t) & 1u)) continue;
    uint32_t rank = pfx[w] + (uint32_t)__popc(kw & ((1u << t) - 1u));
    if (rank >= MAXDET) continue;
    size_t o = (size_t)b * KTOP + r;
    float* orow = out + ((size_t)b * MAXDET + rank) * OUTC;
    orow[0] = s_box[o * 4 + 0];
    orow[1] = s_box[o * 4 + 1];
    orow[2] = s_box[o * 4 + 2];
    orow[3] = s_box[o * 4 + 3];
    orow[4] = s_score[o];
    orow[5] = s_clsf[o];
    const float* lrow = logits + ((size_t)b * NDET + s_n[o]) * NCLS;
    for (int c2 = 0; c2 < NCLS; ++c2) orow[6 + c2] = lrow[c2];
  }
}

extern "C" void kernel_launch(void* const* d_in, const int* in_sizes, int n_in,
                              void* d_out, int out_size, void* d_ws, size_t ws_size,
                              hipStream_t stream) {
  const float* pred = (const float*)d_in[0];
  const float* logits = (const float*)d_in[1];
  float* out = (float*)d_out;

  char* ws = (char*)d_ws;
  size_t off = 0;
  auto alloc = [&](size_t bytes) -> void* {
    void* p = ws + off;
    off += (bytes + 255) & ~(size_t)255;
    return p;
  };
  uint64_t* keys  = (uint64_t*)alloc((size_t)BATCH * NDET * 8);
  uint32_t* sw    = (uint32_t*)alloc((size_t)BATCH * NDET * 4);
  uint32_t* s_n   = (uint32_t*)alloc((size_t)BATCH * KTOP * 4);
  float*    s_sc  = (float*)alloc((size_t)BATCH * KTOP * 4);
  float*    s_cl  = (float*)alloc((size_t)BATCH * KTOP * 4);
  uint32_t* s_cli = (uint32_t*)alloc((size_t)BATCH * KTOP * 4);
  uint32_t* clsbm = (uint32_t*)alloc((size_t)BATCH * BMW * 4);
  float*    s_box = (float*)alloc((size_t)BATCH * KTOP * 16);
  float*    s_ob  = (float*)alloc((size_t)BATCH * KTOP * 16);
  uint32_t* nval  = (uint32_t*)alloc((size_t)BATCH * 4);
  uint32_t* mask  = (uint32_t*)alloc((size_t)BATCH * MROWS * 64 * 4);
  uint32_t* diag  = (uint32_t*)alloc((size_t)BATCH * KTOP * 4);
  uint32_t* suppw = (uint32_t*)alloc((size_t)BATCH * 64 * 4);
  (void)ws_size; (void)in_sizes; (void)n_in;

  hipMemsetAsync(d_out, 0, (size_t)out_size * sizeof(float), stream);

  int total = BATCH * NDET;
  k_keys<<<(total + 255) / 256, 256, 0, stream>>>(pred, keys, sw);
  k_sel<<<BATCH, 1024, 0, stream>>>(keys, sw, pred, s_n, s_sc, s_cl, s_cli, clsbm, s_box, s_ob, nval);
  k_mask<<<(BATCH * KTOP * 64) / 256, 256, 0, stream>>>(s_ob, s_cli, clsbm, nval, mask, diag);
  k_nms<<<BATCH, 64, 0, stream>>>(mask, diag, nval, suppw);
  k_out<<<BATCH, 256, 0, stream>>>(suppw, nval, s_n, s_sc, s_cl, s_box, logits, out);
}